// Round 6
// baseline (414.612 us; speedup 1.0000x reference)
//
#include <hip/hip_runtime.h>
#include <hip/hip_bf16.h>

// ---------------------------------------------------------------------------
// GAT (2 layers) — round 6:
//   * deg_hist/scatter: edge-array reads are NON-TEMPORAL (nt) so the 12.8 MB
//     stream no longer evicts the dirty XCD-local scatter window from L2.
//     (R5 residual: WRITE_SIZE was 10x srcs size due to mid-fill evictions.)
//   * rest = R5: XCD-partitioned CSR build, tiled GEMM, bf16 h, edge-slot agg.
// ---------------------------------------------------------------------------

__device__ __forceinline__ float lrelu02(float x) { return x > 0.f ? x : 0.2f * x; }

__device__ __forceinline__ unsigned short f2bf(float v) {
    __hip_bfloat16 b = __float2bfloat16(v);
    return __builtin_bit_cast(unsigned short, b);
}

// ----------------------------- CSR build -----------------------------------

__global__ void deg_init_kernel(int* __restrict__ deg, int n) {
    int i = blockIdx.x * blockDim.x + threadIdx.x;
    if (i < n) deg[i] = 1;                    // self-loop contributes 1
}

// partition = blockIdx&7 (XCD-exclusive dst window); slice = blockIdx>>3
__global__ void deg_hist_kernel(const int* __restrict__ ei, int e_real,
                                unsigned M, int* __restrict__ deg) {
    const int part   = blockIdx.x & 7;
    const int slice  = blockIdx.x >> 3;
    const int nsl    = gridDim.x >> 3;
    const int stride = nsl * blockDim.x;
    for (int i = slice * blockDim.x + threadIdx.x; i < e_real; i += stride) {
        int dst = __builtin_nontemporal_load(&ei[e_real + i]);
        if ((int)__umulhi((unsigned)dst, M) == part)
            atomicAdd(&deg[dst], 1);
    }
}

__global__ void scan1_kernel(const int* __restrict__ deg,
                             int* __restrict__ local_incl,
                             int* __restrict__ bsum, int n) {
    __shared__ int s[256];
    int tid = threadIdx.x;
    int i = blockIdx.x * 256 + tid;
    int v = (i < n) ? deg[i] : 0;
    s[tid] = v;
    __syncthreads();
    for (int off = 1; off < 256; off <<= 1) {
        int t = (tid >= off) ? s[tid - off] : 0;
        __syncthreads();
        s[tid] += t;
        __syncthreads();
    }
    if (i < n) local_incl[i] = s[tid];
    if (tid == 255) bsum[blockIdx.x] = s[255];
}

__global__ void scan2_kernel(int* __restrict__ bsum, int nb) {
    __shared__ int s[512];
    int tid = threadIdx.x;
    int v = (tid < nb) ? bsum[tid] : 0;
    s[tid] = v;
    __syncthreads();
    for (int off = 1; off < 512; off <<= 1) {
        int t = (tid >= off) ? s[tid - off] : 0;
        __syncthreads();
        s[tid] += t;
        __syncthreads();
    }
    if (tid < nb) bsum[tid] = s[tid] - v;     // exclusive
}

__global__ void scan3_kernel(const int* __restrict__ deg,
                             const int* __restrict__ local_incl,
                             const int* __restrict__ bsum,
                             int* __restrict__ offsets,
                             int* __restrict__ cursor, int n) {
    int i = blockIdx.x * blockDim.x + threadIdx.x;
    if (i >= n) return;
    int excl = bsum[i >> 8] + local_incl[i] - deg[i];
    offsets[i] = excl;
    cursor[i]  = excl;
    if (i == n - 1) offsets[n] = bsum[i >> 8] + local_incl[i];
}

// partitioned like deg_hist: each XCD owns a contiguous srcs/cursor window
__global__ void scatter_kernel(const int* __restrict__ ei,
                               int e_real, int e_total, unsigned M,
                               int* __restrict__ cursor,
                               int* __restrict__ srcs) {
    const int part   = blockIdx.x & 7;
    const int slice  = blockIdx.x >> 3;
    const int nsl    = gridDim.x >> 3;
    const int stride = nsl * blockDim.x;
    for (int i = slice * blockDim.x + threadIdx.x; i < e_total; i += stride) {
        int src, dst;
        if (i < e_real) {
            dst = __builtin_nontemporal_load(&ei[e_real + i]);
        } else {
            dst = i - e_real;
        }
        if ((int)__umulhi((unsigned)dst, M) == part) {
            src = (i < e_real) ? __builtin_nontemporal_load(&ei[i]) : dst;
            int pos = atomicAdd(&cursor[dst], 1);
            srcs[pos] = src;
        }
    }
}

// ------------------------- tiled GEMM + attention logits --------------------
template<int K, int OUTC, int H, int C, int NPT, int KCHUNK>
__global__ __launch_bounds__(256)
void gemm_al_kernel(const float* __restrict__ x,
                    const float* __restrict__ W,
                    const float* __restrict__ a_src,
                    const float* __restrict__ a_dst,
                    unsigned short* __restrict__ h,      // [n][OUTC] bf16
                    float* __restrict__ al_s,
                    float* __restrict__ al_d,
                    int n) {
    constexpr int COLG = OUTC / 4;
    constexpr int NG   = 256 / COLG;
    static_assert(NG * 8 == NPT, "tile mismatch");
    constexpr int LDX  = KCHUNK + 1;
    __shared__ float Xs[NPT * LDX];
    __shared__ float Ws[KCHUNK * OUTC];

    const int t    = threadIdx.x;
    const int mg   = t / COLG;
    const int cg   = t % COLG;
    const int base = blockIdx.x * NPT;

    float acc[8][4];
#pragma unroll
    for (int i = 0; i < 8; ++i)
#pragma unroll
        for (int j = 0; j < 4; ++j) acc[i][j] = 0.f;

    for (int kc = 0; kc < K; kc += KCHUNK) {
        __syncthreads();
        constexpr int F4R = KCHUNK / 4;
        constexpr int TOTF4 = NPT * F4R;
#pragma unroll
        for (int r = 0; r < TOTF4 / 256; ++r) {
            int f4   = r * 256 + t;
            int node = f4 / F4R;
            int kq   = f4 % F4R;
            int gn   = base + node; if (gn > n - 1) gn = n - 1;
            const float4 v = *(const float4*)&x[(size_t)gn * K + kc + kq * 4];
            float* d = &Xs[node * LDX + kq * 4];
            d[0] = v.x; d[1] = v.y; d[2] = v.z; d[3] = v.w;
        }
        constexpr int WF4 = KCHUNK * OUTC / 4;
        for (int idx = t; idx < WF4; idx += 256)
            *(float4*)&Ws[idx * 4] = *(const float4*)&W[(size_t)kc * OUTC + idx * 4];
        __syncthreads();

#pragma unroll 4
        for (int k = 0; k < KCHUNK; ++k) {
            float4 b = *(const float4*)&Ws[k * OUTC + cg * 4];
            float a[8];
#pragma unroll
            for (int i = 0; i < 8; ++i) a[i] = Xs[(mg * 8 + i) * LDX + k];
#pragma unroll
            for (int i = 0; i < 8; ++i) {
                acc[i][0] += a[i] * b.x;
                acc[i][1] += a[i] * b.y;
                acc[i][2] += a[i] * b.z;
                acc[i][3] += a[i] * b.w;
            }
        }
    }

    const float4 as4 = *(const float4*)&a_src[cg * 4];
    const float4 ad4 = *(const float4*)&a_dst[cg * 4];
    constexpr int GPH = C / 4;
    const int head = cg / GPH;
#pragma unroll
    for (int i = 0; i < 8; ++i) {
        int gn = base + mg * 8 + i;
        bool ok = gn < n;
        if (ok) {
            ushort4 hv;
            hv.x = f2bf(acc[i][0]); hv.y = f2bf(acc[i][1]);
            hv.z = f2bf(acc[i][2]); hv.w = f2bf(acc[i][3]);
            *(ushort4*)&h[(size_t)gn * OUTC + cg * 4] = hv;
        }
        float ps = acc[i][0] * as4.x + acc[i][1] * as4.y +
                   acc[i][2] * as4.z + acc[i][3] * as4.w;
        float pd = acc[i][0] * ad4.x + acc[i][1] * ad4.y +
                   acc[i][2] * ad4.z + acc[i][3] * ad4.w;
#pragma unroll
        for (int s = 1; s < GPH; s <<= 1) {
            ps += __shfl_xor(ps, s, 64);
            pd += __shfl_xor(pd, s, 64);
        }
        if (ok && (cg % GPH) == 0) {
            al_s[(size_t)gn * H + head] = ps;
            al_d[(size_t)gn * H + head] = pd;
        }
    }
}

// ------------------------- fused gather aggregation -------------------------
// wave = 1 dst node; lane = (edge_slot es, channel_group cg of 8 bf16).
template<int H, int C>
__global__ __launch_bounds__(256)
void gat_agg_kernel(const int* __restrict__ offsets,
                    const int* __restrict__ srcs,
                    const float* __restrict__ al_s,
                    const float* __restrict__ al_d,
                    const unsigned short* __restrict__ hfeat, // bf16
                    const float* __restrict__ bias,
                    float* __restrict__ out, int n) {
    constexpr int OUTC = H * C;
    constexpr int CG   = OUTC / 8;           // channel groups (8 or 4)
    constexpr int ES   = 64 / CG;            // edge slots (8 or 16)
    const int wid  = (int)((blockIdx.x * blockDim.x + threadIdx.x) >> 6);
    const int lane = threadIdx.x & 63;
    const int cg   = lane % CG;
    const int es   = lane / CG;
    if (wid >= n) return;
    const int head = (cg * 8) / C;

    const float aldv = al_d[(size_t)wid * H + head];
    const int beg = offsets[wid];
    const int end = offsets[wid + 1];

    float acc[8];
#pragma unroll
    for (int q = 0; q < 8; ++q) acc[q] = 0.f;
    float dsum = 0.f;

    for (int j0 = beg; j0 < end; j0 += ES) {
        int j = j0 + es;
        bool v = j < end;
        int s = srcs[v ? j : beg];           // clamp -> dup address, cache hit
        float ex = v ? __expf(lrelu02(al_s[(size_t)s * H + head] + aldv)) : 0.f;
        const uint4 hv = *(const uint4*)&hfeat[(size_t)s * OUTC + cg * 8];
        unsigned du[4] = {hv.x, hv.y, hv.z, hv.w};
#pragma unroll
        for (int q = 0; q < 4; ++q) {
            float flo = __uint_as_float(du[q] << 16);
            float fhi = __uint_as_float(du[q] & 0xffff0000u);
            acc[2 * q]     += flo * ex;
            acc[2 * q + 1] += fhi * ex;
        }
        dsum += ex;
    }

#pragma unroll
    for (int sh = CG; sh < 64; sh <<= 1) {
        dsum += __shfl_xor(dsum, sh, 64);
#pragma unroll
        for (int q = 0; q < 8; ++q) acc[q] += __shfl_xor(acc[q], sh, 64);
    }

    if (es == 0) {
        float inv = 1.f / dsum;
        float4 o0, o1;
        o0.x = acc[0] * inv + bias[cg * 8 + 0];
        o0.y = acc[1] * inv + bias[cg * 8 + 1];
        o0.z = acc[2] * inv + bias[cg * 8 + 2];
        o0.w = acc[3] * inv + bias[cg * 8 + 3];
        o1.x = acc[4] * inv + bias[cg * 8 + 4];
        o1.y = acc[5] * inv + bias[cg * 8 + 5];
        o1.z = acc[6] * inv + bias[cg * 8 + 6];
        o1.w = acc[7] * inv + bias[cg * 8 + 7];
        *(float4*)&out[(size_t)wid * OUTC + cg * 8]     = o0;
        *(float4*)&out[(size_t)wid * OUTC + cg * 8 + 4] = o1;
    }
}

// ---------------------------------------------------------------------------

extern "C" void kernel_launch(void* const* d_in, const int* in_sizes, int n_in,
                              void* d_out, int out_size, void* d_ws, size_t ws_size,
                              hipStream_t stream) {
    const float* x   = (const float*)d_in[0];
    const int*   ei  = (const int*)  d_in[1];
    const float* W1  = (const float*)d_in[2];
    const float* as1 = (const float*)d_in[3];
    const float* ad1 = (const float*)d_in[4];
    const float* b1  = (const float*)d_in[5];
    const float* W2  = (const float*)d_in[6];
    const float* as2 = (const float*)d_in[7];
    const float* ad2 = (const float*)d_in[8];
    const float* b2  = (const float*)d_in[9];
    float* out = (float*)d_out;

    const int n       = in_sizes[0] / 128;   // 100000
    const int e_real  = in_sizes[1] / 2;     // 1600000
    const int e_total = e_real + n;
    const int NB      = (n + 255) / 256;     // scan blocks (391 <= 512)
    // monotone dst -> partition in [0,8): part = umulhi(dst, M8)
    const unsigned M8 = (unsigned)((8ull << 32) / (unsigned)n);

    // ------------- workspace layout -------------
    unsigned short* h1u = (unsigned short*)d_ws;       // n*64 bf16 (l2: n*32)
    float* fws  = (float*)d_ws;
    float* als1 = fws  + (size_t)n * 32;               // n*8  (l2: n)
    float* ald1 = als1 + (size_t)n * 8;                // n*8  (l2: n)
    float* agg1 = ald1 + (size_t)n * 8;                // n*64 fp32 (layer1 out)
    int* offsets  = (int*)(agg1 + (size_t)n * 64);     // n+1
    int* cursor   = offsets + (n + 1);                 // n
    int* deg      = cursor + n;                        // n
    int* lincl    = deg + n;                           // n
    int* bsum     = lincl + n;                         // 512
    int* srcs     = bsum + 512;                        // e_total

    const int nb256 = (n + 255) / 256;
    const int PART_BLOCKS = 8 * 120;                   // 120 slices per partition

    // ------------- CSR build (shared by both layers) -------------
    deg_init_kernel<<<nb256, 256, 0, stream>>>(deg, n);
    deg_hist_kernel<<<PART_BLOCKS, 256, 0, stream>>>(ei, e_real, M8, deg);
    scan1_kernel<<<NB, 256, 0, stream>>>(deg, lincl, bsum, n);
    scan2_kernel<<<1, 512, 0, stream>>>(bsum, NB);
    scan3_kernel<<<nb256, 256, 0, stream>>>(deg, lincl, bsum, offsets, cursor, n);
    scatter_kernel<<<PART_BLOCKS, 256, 0, stream>>>(ei, e_real, e_total, M8,
                                                    cursor, srcs);

    // ------------- layer 1: K=128, H=8, C=8 -------------
    gemm_al_kernel<128, 64, 8, 8, 128, 64><<<(n + 127) / 128, 256, 0, stream>>>(
        x, W1, as1, ad1, h1u, als1, ald1, n);
    gat_agg_kernel<8, 8><<<(n + 3) / 4, 256, 0, stream>>>(
        offsets, srcs, als1, ald1, h1u, b1, agg1, n);

    // ------------- layer 2: K=64, H=1, C=32 -------------
    gemm_al_kernel<64, 32, 1, 32, 256, 32><<<(n + 255) / 256, 256, 0, stream>>>(
        agg1, W2, as2, ad2, h1u, als1, ald1, n);
    gat_agg_kernel<1, 32><<<(n + 3) / 4, 256, 0, stream>>>(
        offsets, srcs, als1, ald1, h1u, b2, out, n);
}

// Round 7
// 314.643 us; speedup vs baseline: 1.3177x; 1.3177x over previous
//
#include <hip/hip_runtime.h>
#include <hip/hip_bf16.h>

// ---------------------------------------------------------------------------
// GAT (2 layers) — round 7:
//   * CSR build rewritten as 2-phase bucket sort (256 dst-range buckets):
//     hist -> scan -> LDS-staged chunk scatter (coalesced line-run writes of
//     (src,dst) pairs) -> per-bucket finalize (LDS deg+scan+cursor; writes
//     offsets AND srcs with zero global atomics; each srcs line has exactly
//     one writer block -> 1x writeback). Replaces deg/scan/scatter chain.
//   * pairs scratch aliases agg1 region (dead during CSR build).
//   * rest = R5: tiled GEMM, bf16 h, edge-slot gather aggregation.
// ---------------------------------------------------------------------------

__device__ __forceinline__ float lrelu02(float x) { return x > 0.f ? x : 0.2f * x; }

__device__ __forceinline__ unsigned short f2bf(float v) {
    __hip_bfloat16 b = __float2bfloat16(v);
    return __builtin_bit_cast(unsigned short, b);
}

// ----------------------------- CSR build (bucket sort) ----------------------
// bucket(d) = umulhi(d, M) with M = floor(2^32 * 256 / n) -> 256 monotone
// dst ranges of ~n/256 (<512) nodes each.

__global__ void bucket_hist_kernel(const int* __restrict__ ei, int e_real,
                                   int e_total, unsigned M,
                                   int* __restrict__ bcnt_pad) {
    __shared__ int cnt[256];
    const int t = threadIdx.x;
    cnt[t] = 0;
    __syncthreads();
    const int stride = gridDim.x * blockDim.x;
    for (int i = blockIdx.x * blockDim.x + t; i < e_total; i += stride) {
        int dst = (i < e_real) ? ei[e_real + i] : i - e_real;
        atomicAdd(&cnt[__umulhi((unsigned)dst, M)], 1);
    }
    __syncthreads();
    if (cnt[t]) atomicAdd(&bcnt_pad[t * 16], cnt[t]);
}

__global__ void bucket_scan_kernel(const int* __restrict__ bcnt_pad,
                                   int* __restrict__ boff,
                                   int* __restrict__ bcur_pad) {
    __shared__ int s[256];
    const int t = threadIdx.x;
    int c = bcnt_pad[t * 16];
    s[t] = c;
    __syncthreads();
    for (int off = 1; off < 256; off <<= 1) {
        int v = (t >= off) ? s[t - off] : 0;
        __syncthreads();
        s[t] += v;
        __syncthreads();
    }
    int excl = s[t] - c;
    boff[t] = excl;
    bcur_pad[t * 16] = excl;
    if (t == 255) boff[256] = s[255];
}

// chunk = 4096 edges/block; stage sorted-by-bucket in LDS, reserve one
// contiguous global range per bucket, flush coalesced runs.
__global__ __launch_bounds__(256)
void bucket_scatter_kernel(const int* __restrict__ ei, int e_real, int e_total,
                           unsigned M, int* __restrict__ bcur_pad,
                           int2* __restrict__ pairs) {
    __shared__ int cnt[256], loff[256], lcur[256], gbase[256];
    __shared__ int2 stag[4096];
    __shared__ unsigned short bb[4096];
    const int t = threadIdx.x;
    const int base = blockIdx.x * 4096;
    cnt[t] = 0;
    __syncthreads();

    int rs[16], rd[16], rb[16];
#pragma unroll
    for (int k = 0; k < 16; ++k) {
        int i = base + k * 256 + t;
        bool val = i < e_total;
        int s = 0, d = 0;
        if (val) {
            if (i < e_real) { s = ei[i]; d = ei[e_real + i]; }
            else            { s = d = i - e_real; }
        }
        int b = val ? (int)__umulhi((unsigned)d, M) : -1;
        rs[k] = s; rd[k] = d; rb[k] = b;
        if (val) atomicAdd(&cnt[b], 1);
    }
    __syncthreads();

    loff[t] = cnt[t];
    __syncthreads();
    for (int off = 1; off < 256; off <<= 1) {
        int v = (t >= off) ? loff[t - off] : 0;
        __syncthreads();
        loff[t] += v;
        __syncthreads();
    }
    int excl = loff[t] - cnt[t];
    __syncthreads();
    loff[t] = excl;
    lcur[t] = excl;
    gbase[t] = atomicAdd(&bcur_pad[t * 16], cnt[t]);   // one atomic per bucket
    __syncthreads();

#pragma unroll
    for (int k = 0; k < 16; ++k) {
        if (rb[k] >= 0) {
            int lp = atomicAdd(&lcur[rb[k]], 1);
            stag[lp] = make_int2(rs[k], rd[k]);
            bb[lp]   = (unsigned short)rb[k];
        }
    }
    __syncthreads();

    int cn = e_total - base; if (cn > 4096) cn = 4096;
    for (int idx = t; idx < cn; idx += 256) {
        int b = bb[idx];
        int g = gbase[b] + (idx - loff[b]);
        pairs[g] = stag[idx];                           // coalesced runs
    }
}

// one block per bucket: deg-count + scan in LDS -> offsets; scatter srcs in a
// private ~26 KB window with LDS cursors (no global atomics, 1x writeback).
__global__ __launch_bounds__(256)
void csr_finalize_kernel(const int2* __restrict__ pairs,
                         const int* __restrict__ boff,
                         unsigned M, int n,
                         int* __restrict__ offsets,
                         int* __restrict__ srcs) {
    const int b = blockIdx.x;
    const int t = threadIdx.x;
    const unsigned long long Mll = M;
    int lo = (int)((((unsigned long long)b << 32) + Mll - 1) / Mll);
    int hi = (int)((((unsigned long long)(b + 1) << 32) + Mll - 1) / Mll);
    if (lo > n) lo = n;
    if (hi > n) hi = n;
    const int R    = hi - lo;                 // <= ~392 < 512
    const int ebeg = boff[b];
    const int eend = boff[b + 1];

    __shared__ int deg[512], sc[512], cur[512];
    deg[t] = 0; deg[t + 256] = 0;
    __syncthreads();
    for (int j = ebeg + t; j < eend; j += 256)
        atomicAdd(&deg[pairs[j].y - lo], 1);
    __syncthreads();

    sc[t] = deg[t]; sc[t + 256] = deg[t + 256];
    __syncthreads();
    for (int off = 1; off < 512; off <<= 1) {
        int v0 = (t >= off) ? sc[t - off] : 0;
        int v1 = (t + 256 >= off) ? sc[t + 256 - off] : 0;
        __syncthreads();
        sc[t] += v0; sc[t + 256] += v1;
        __syncthreads();
    }
    int e0 = sc[t] - deg[t];
    int e1 = sc[t + 256] - deg[t + 256];
    cur[t] = e0; cur[t + 256] = e1;
    if (t < R)       offsets[lo + t]       = ebeg + e0;
    if (t + 256 < R) offsets[lo + t + 256] = ebeg + e1;
    if (b == 255 && t == 0) offsets[n] = eend;
    __syncthreads();

    for (int j = ebeg + t; j < eend; j += 256) {
        int2 p = pairs[j];
        int pos = atomicAdd(&cur[p.y - lo], 1);         // LDS atomic
        srcs[ebeg + pos] = p.x;
    }
}

// ------------------------- tiled GEMM + attention logits --------------------
template<int K, int OUTC, int H, int C, int NPT, int KCHUNK>
__global__ __launch_bounds__(256)
void gemm_al_kernel(const float* __restrict__ x,
                    const float* __restrict__ W,
                    const float* __restrict__ a_src,
                    const float* __restrict__ a_dst,
                    unsigned short* __restrict__ h,      // [n][OUTC] bf16
                    float* __restrict__ al_s,
                    float* __restrict__ al_d,
                    int n) {
    constexpr int COLG = OUTC / 4;
    constexpr int NG   = 256 / COLG;
    static_assert(NG * 8 == NPT, "tile mismatch");
    constexpr int LDX  = KCHUNK + 1;
    __shared__ float Xs[NPT * LDX];
    __shared__ float Ws[KCHUNK * OUTC];

    const int t    = threadIdx.x;
    const int mg   = t / COLG;
    const int cg   = t % COLG;
    const int base = blockIdx.x * NPT;

    float acc[8][4];
#pragma unroll
    for (int i = 0; i < 8; ++i)
#pragma unroll
        for (int j = 0; j < 4; ++j) acc[i][j] = 0.f;

    for (int kc = 0; kc < K; kc += KCHUNK) {
        __syncthreads();
        constexpr int F4R = KCHUNK / 4;
        constexpr int TOTF4 = NPT * F4R;
#pragma unroll
        for (int r = 0; r < TOTF4 / 256; ++r) {
            int f4   = r * 256 + t;
            int node = f4 / F4R;
            int kq   = f4 % F4R;
            int gn   = base + node; if (gn > n - 1) gn = n - 1;
            const float4 v = *(const float4*)&x[(size_t)gn * K + kc + kq * 4];
            float* d = &Xs[node * LDX + kq * 4];
            d[0] = v.x; d[1] = v.y; d[2] = v.z; d[3] = v.w;
        }
        constexpr int WF4 = KCHUNK * OUTC / 4;
        for (int idx = t; idx < WF4; idx += 256)
            *(float4*)&Ws[idx * 4] = *(const float4*)&W[(size_t)kc * OUTC + idx * 4];
        __syncthreads();

#pragma unroll 4
        for (int k = 0; k < KCHUNK; ++k) {
            float4 b = *(const float4*)&Ws[k * OUTC + cg * 4];
            float a[8];
#pragma unroll
            for (int i = 0; i < 8; ++i) a[i] = Xs[(mg * 8 + i) * LDX + k];
#pragma unroll
            for (int i = 0; i < 8; ++i) {
                acc[i][0] += a[i] * b.x;
                acc[i][1] += a[i] * b.y;
                acc[i][2] += a[i] * b.z;
                acc[i][3] += a[i] * b.w;
            }
        }
    }

    const float4 as4 = *(const float4*)&a_src[cg * 4];
    const float4 ad4 = *(const float4*)&a_dst[cg * 4];
    constexpr int GPH = C / 4;
    const int head = cg / GPH;
#pragma unroll
    for (int i = 0; i < 8; ++i) {
        int gn = base + mg * 8 + i;
        bool ok = gn < n;
        if (ok) {
            ushort4 hv;
            hv.x = f2bf(acc[i][0]); hv.y = f2bf(acc[i][1]);
            hv.z = f2bf(acc[i][2]); hv.w = f2bf(acc[i][3]);
            *(ushort4*)&h[(size_t)gn * OUTC + cg * 4] = hv;
        }
        float ps = acc[i][0] * as4.x + acc[i][1] * as4.y +
                   acc[i][2] * as4.z + acc[i][3] * as4.w;
        float pd = acc[i][0] * ad4.x + acc[i][1] * ad4.y +
                   acc[i][2] * ad4.z + acc[i][3] * ad4.w;
#pragma unroll
        for (int s = 1; s < GPH; s <<= 1) {
            ps += __shfl_xor(ps, s, 64);
            pd += __shfl_xor(pd, s, 64);
        }
        if (ok && (cg % GPH) == 0) {
            al_s[(size_t)gn * H + head] = ps;
            al_d[(size_t)gn * H + head] = pd;
        }
    }
}

// ------------------------- fused gather aggregation -------------------------
// wave = 1 dst node; lane = (edge_slot es, channel_group cg of 8 bf16).
template<int H, int C>
__global__ __launch_bounds__(256)
void gat_agg_kernel(const int* __restrict__ offsets,
                    const int* __restrict__ srcs,
                    const float* __restrict__ al_s,
                    const float* __restrict__ al_d,
                    const unsigned short* __restrict__ hfeat, // bf16
                    const float* __restrict__ bias,
                    float* __restrict__ out, int n) {
    constexpr int OUTC = H * C;
    constexpr int CG   = OUTC / 8;           // channel groups (8 or 4)
    constexpr int ES   = 64 / CG;            // edge slots (8 or 16)
    const int wid  = (int)((blockIdx.x * blockDim.x + threadIdx.x) >> 6);
    const int lane = threadIdx.x & 63;
    const int cg   = lane % CG;
    const int es   = lane / CG;
    if (wid >= n) return;
    const int head = (cg * 8) / C;

    const float aldv = al_d[(size_t)wid * H + head];
    const int beg = offsets[wid];
    const int end = offsets[wid + 1];

    float acc[8];
#pragma unroll
    for (int q = 0; q < 8; ++q) acc[q] = 0.f;
    float dsum = 0.f;

    for (int j0 = beg; j0 < end; j0 += ES) {
        int j = j0 + es;
        bool v = j < end;
        int s = srcs[v ? j : beg];           // clamp -> dup address, cache hit
        float ex = v ? __expf(lrelu02(al_s[(size_t)s * H + head] + aldv)) : 0.f;
        const uint4 hv = *(const uint4*)&hfeat[(size_t)s * OUTC + cg * 8];
        unsigned du[4] = {hv.x, hv.y, hv.z, hv.w};
#pragma unroll
        for (int q = 0; q < 4; ++q) {
            float flo = __uint_as_float(du[q] << 16);
            float fhi = __uint_as_float(du[q] & 0xffff0000u);
            acc[2 * q]     += flo * ex;
            acc[2 * q + 1] += fhi * ex;
        }
        dsum += ex;
    }

#pragma unroll
    for (int sh = CG; sh < 64; sh <<= 1) {
        dsum += __shfl_xor(dsum, sh, 64);
#pragma unroll
        for (int q = 0; q < 8; ++q) acc[q] += __shfl_xor(acc[q], sh, 64);
    }

    if (es == 0) {
        float inv = 1.f / dsum;
        float4 o0, o1;
        o0.x = acc[0] * inv + bias[cg * 8 + 0];
        o0.y = acc[1] * inv + bias[cg * 8 + 1];
        o0.z = acc[2] * inv + bias[cg * 8 + 2];
        o0.w = acc[3] * inv + bias[cg * 8 + 3];
        o1.x = acc[4] * inv + bias[cg * 8 + 4];
        o1.y = acc[5] * inv + bias[cg * 8 + 5];
        o1.z = acc[6] * inv + bias[cg * 8 + 6];
        o1.w = acc[7] * inv + bias[cg * 8 + 7];
        *(float4*)&out[(size_t)wid * OUTC + cg * 8]     = o0;
        *(float4*)&out[(size_t)wid * OUTC + cg * 8 + 4] = o1;
    }
}

// ---------------------------------------------------------------------------

extern "C" void kernel_launch(void* const* d_in, const int* in_sizes, int n_in,
                              void* d_out, int out_size, void* d_ws, size_t ws_size,
                              hipStream_t stream) {
    const float* x   = (const float*)d_in[0];
    const int*   ei  = (const int*)  d_in[1];
    const float* W1  = (const float*)d_in[2];
    const float* as1 = (const float*)d_in[3];
    const float* ad1 = (const float*)d_in[4];
    const float* b1  = (const float*)d_in[5];
    const float* W2  = (const float*)d_in[6];
    const float* as2 = (const float*)d_in[7];
    const float* ad2 = (const float*)d_in[8];
    const float* b2  = (const float*)d_in[9];
    float* out = (float*)d_out;

    const int n       = in_sizes[0] / 128;   // 100000
    const int e_real  = in_sizes[1] / 2;     // 1600000
    const int e_total = e_real + n;
    // bucket(d) = umulhi(d, M256): 256 monotone dst ranges
    const unsigned M256 = (unsigned)((256ull << 32) / (unsigned)n);

    // ------------- workspace layout -------------
    unsigned short* h1u = (unsigned short*)d_ws;       // n*64 bf16 (l2: n*32)
    float* fws  = (float*)d_ws;
    float* als1 = fws  + (size_t)n * 32;               // n*8  (l2: n)
    float* ald1 = als1 + (size_t)n * 8;                // n*8  (l2: n)
    float* agg1 = ald1 + (size_t)n * 8;                // n*64 fp32 (layer1 out)
    int2*  pairs = (int2*)agg1;                        // ALIAS: e_total int2
    int* offsets  = (int*)(agg1 + (size_t)n * 64);     // n+1
    int* srcs     = offsets + (n + 1);                 // e_total
    int* bcnt_pad = srcs + e_total;                    // 256*16
    int* bcur_pad = bcnt_pad + 256 * 16;               // 256*16
    int* boff     = bcur_pad + 256 * 16;               // 257

    // ------------- CSR build (bucket sort; shared by both layers) -----------
    hipMemsetAsync(bcnt_pad, 0, 256 * 16 * sizeof(int), stream);
    bucket_hist_kernel<<<512, 256, 0, stream>>>(ei, e_real, e_total, M256,
                                                bcnt_pad);
    bucket_scan_kernel<<<1, 256, 0, stream>>>(bcnt_pad, boff, bcur_pad);
    bucket_scatter_kernel<<<(e_total + 4095) / 4096, 256, 0, stream>>>(
        ei, e_real, e_total, M256, bcur_pad, pairs);
    csr_finalize_kernel<<<256, 256, 0, stream>>>(pairs, boff, M256, n,
                                                 offsets, srcs);

    // ------------- layer 1: K=128, H=8, C=8 -------------
    gemm_al_kernel<128, 64, 8, 8, 128, 64><<<(n + 127) / 128, 256, 0, stream>>>(
        x, W1, as1, ad1, h1u, als1, ald1, n);
    gat_agg_kernel<8, 8><<<(n + 3) / 4, 256, 0, stream>>>(
        offsets, srcs, als1, ald1, h1u, b1, agg1, n);

    // ------------- layer 2: K=64, H=1, C=32 -------------
    gemm_al_kernel<64, 32, 1, 32, 256, 32><<<(n + 255) / 256, 256, 0, stream>>>(
        agg1, W2, as2, ad2, h1u, als1, ald1, n);
    gat_agg_kernel<1, 32><<<(n + 3) / 4, 256, 0, stream>>>(
        offsets, srcs, als1, ald1, h1u, b2, out, n);
}

// Round 8
// 301.080 us; speedup vs baseline: 1.3771x; 1.0450x over previous
//
#include <hip/hip_runtime.h>
#include <hip/hip_bf16.h>

// ---------------------------------------------------------------------------
// GAT (2 layers) — round 8:
//   * gat_agg: 2xES edge batching per iteration (16/32 gathers in flight per
//     wave) + non-temporal srcs streaming (single-use; keeps h/al_s in L2).
//   * rest = R7: bucket-sort CSR build, tiled fp32 GEMM, bf16 h.
// ---------------------------------------------------------------------------

__device__ __forceinline__ float lrelu02(float x) { return x > 0.f ? x : 0.2f * x; }

__device__ __forceinline__ unsigned short f2bf(float v) {
    __hip_bfloat16 b = __float2bfloat16(v);
    return __builtin_bit_cast(unsigned short, b);
}

// ----------------------------- CSR build (bucket sort) ----------------------

__global__ void bucket_hist_kernel(const int* __restrict__ ei, int e_real,
                                   int e_total, unsigned M,
                                   int* __restrict__ bcnt_pad) {
    __shared__ int cnt[256];
    const int t = threadIdx.x;
    cnt[t] = 0;
    __syncthreads();
    const int stride = gridDim.x * blockDim.x;
    for (int i = blockIdx.x * blockDim.x + t; i < e_total; i += stride) {
        int dst = (i < e_real) ? ei[e_real + i] : i - e_real;
        atomicAdd(&cnt[__umulhi((unsigned)dst, M)], 1);
    }
    __syncthreads();
    if (cnt[t]) atomicAdd(&bcnt_pad[t * 16], cnt[t]);
}

__global__ void bucket_scan_kernel(const int* __restrict__ bcnt_pad,
                                   int* __restrict__ boff,
                                   int* __restrict__ bcur_pad) {
    __shared__ int s[256];
    const int t = threadIdx.x;
    int c = bcnt_pad[t * 16];
    s[t] = c;
    __syncthreads();
    for (int off = 1; off < 256; off <<= 1) {
        int v = (t >= off) ? s[t - off] : 0;
        __syncthreads();
        s[t] += v;
        __syncthreads();
    }
    int excl = s[t] - c;
    boff[t] = excl;
    bcur_pad[t * 16] = excl;
    if (t == 255) boff[256] = s[255];
}

__global__ __launch_bounds__(256)
void bucket_scatter_kernel(const int* __restrict__ ei, int e_real, int e_total,
                           unsigned M, int* __restrict__ bcur_pad,
                           int2* __restrict__ pairs) {
    __shared__ int cnt[256], loff[256], lcur[256], gbase[256];
    __shared__ int2 stag[4096];
    __shared__ unsigned short bb[4096];
    const int t = threadIdx.x;
    const int base = blockIdx.x * 4096;
    cnt[t] = 0;
    __syncthreads();

    int rs[16], rd[16], rb[16];
#pragma unroll
    for (int k = 0; k < 16; ++k) {
        int i = base + k * 256 + t;
        bool val = i < e_total;
        int s = 0, d = 0;
        if (val) {
            if (i < e_real) { s = ei[i]; d = ei[e_real + i]; }
            else            { s = d = i - e_real; }
        }
        int b = val ? (int)__umulhi((unsigned)d, M) : -1;
        rs[k] = s; rd[k] = d; rb[k] = b;
        if (val) atomicAdd(&cnt[b], 1);
    }
    __syncthreads();

    loff[t] = cnt[t];
    __syncthreads();
    for (int off = 1; off < 256; off <<= 1) {
        int v = (t >= off) ? loff[t - off] : 0;
        __syncthreads();
        loff[t] += v;
        __syncthreads();
    }
    int excl = loff[t] - cnt[t];
    __syncthreads();
    loff[t] = excl;
    lcur[t] = excl;
    gbase[t] = atomicAdd(&bcur_pad[t * 16], cnt[t]);   // one atomic per bucket
    __syncthreads();

#pragma unroll
    for (int k = 0; k < 16; ++k) {
        if (rb[k] >= 0) {
            int lp = atomicAdd(&lcur[rb[k]], 1);
            stag[lp] = make_int2(rs[k], rd[k]);
            bb[lp]   = (unsigned short)rb[k];
        }
    }
    __syncthreads();

    int cn = e_total - base; if (cn > 4096) cn = 4096;
    for (int idx = t; idx < cn; idx += 256) {
        int b = bb[idx];
        int g = gbase[b] + (idx - loff[b]);
        pairs[g] = stag[idx];                           // coalesced runs
    }
}

__global__ __launch_bounds__(256)
void csr_finalize_kernel(const int2* __restrict__ pairs,
                         const int* __restrict__ boff,
                         unsigned M, int n,
                         int* __restrict__ offsets,
                         int* __restrict__ srcs) {
    const int b = blockIdx.x;
    const int t = threadIdx.x;
    const unsigned long long Mll = M;
    int lo = (int)((((unsigned long long)b << 32) + Mll - 1) / Mll);
    int hi = (int)((((unsigned long long)(b + 1) << 32) + Mll - 1) / Mll);
    if (lo > n) lo = n;
    if (hi > n) hi = n;
    const int R    = hi - lo;                 // <= ~392 < 512
    const int ebeg = boff[b];
    const int eend = boff[b + 1];

    __shared__ int deg[512], sc[512], cur[512];
    deg[t] = 0; deg[t + 256] = 0;
    __syncthreads();
    for (int j = ebeg + t; j < eend; j += 256)
        atomicAdd(&deg[pairs[j].y - lo], 1);
    __syncthreads();

    sc[t] = deg[t]; sc[t + 256] = deg[t + 256];
    __syncthreads();
    for (int off = 1; off < 512; off <<= 1) {
        int v0 = (t >= off) ? sc[t - off] : 0;
        int v1 = (t + 256 >= off) ? sc[t + 256 - off] : 0;
        __syncthreads();
        sc[t] += v0; sc[t + 256] += v1;
        __syncthreads();
    }
    int e0 = sc[t] - deg[t];
    int e1 = sc[t + 256] - deg[t + 256];
    cur[t] = e0; cur[t + 256] = e1;
    if (t < R)       offsets[lo + t]       = ebeg + e0;
    if (t + 256 < R) offsets[lo + t + 256] = ebeg + e1;
    if (b == 255 && t == 0) offsets[n] = eend;
    __syncthreads();

    for (int j = ebeg + t; j < eend; j += 256) {
        int2 p = pairs[j];
        int pos = atomicAdd(&cur[p.y - lo], 1);         // LDS atomic
        srcs[ebeg + pos] = p.x;
    }
}

// ------------------------- tiled GEMM + attention logits --------------------
template<int K, int OUTC, int H, int C, int NPT, int KCHUNK>
__global__ __launch_bounds__(256)
void gemm_al_kernel(const float* __restrict__ x,
                    const float* __restrict__ W,
                    const float* __restrict__ a_src,
                    const float* __restrict__ a_dst,
                    unsigned short* __restrict__ h,      // [n][OUTC] bf16
                    float* __restrict__ al_s,
                    float* __restrict__ al_d,
                    int n) {
    constexpr int COLG = OUTC / 4;
    constexpr int NG   = 256 / COLG;
    static_assert(NG * 8 == NPT, "tile mismatch");
    constexpr int LDX  = KCHUNK + 1;
    __shared__ float Xs[NPT * LDX];
    __shared__ float Ws[KCHUNK * OUTC];

    const int t    = threadIdx.x;
    const int mg   = t / COLG;
    const int cg   = t % COLG;
    const int base = blockIdx.x * NPT;

    float acc[8][4];
#pragma unroll
    for (int i = 0; i < 8; ++i)
#pragma unroll
        for (int j = 0; j < 4; ++j) acc[i][j] = 0.f;

    for (int kc = 0; kc < K; kc += KCHUNK) {
        __syncthreads();
        constexpr int F4R = KCHUNK / 4;
        constexpr int TOTF4 = NPT * F4R;
#pragma unroll
        for (int r = 0; r < TOTF4 / 256; ++r) {
            int f4   = r * 256 + t;
            int node = f4 / F4R;
            int kq   = f4 % F4R;
            int gn   = base + node; if (gn > n - 1) gn = n - 1;
            const float4 v = *(const float4*)&x[(size_t)gn * K + kc + kq * 4];
            float* d = &Xs[node * LDX + kq * 4];
            d[0] = v.x; d[1] = v.y; d[2] = v.z; d[3] = v.w;
        }
        constexpr int WF4 = KCHUNK * OUTC / 4;
        for (int idx = t; idx < WF4; idx += 256)
            *(float4*)&Ws[idx * 4] = *(const float4*)&W[(size_t)kc * OUTC + idx * 4];
        __syncthreads();

#pragma unroll 4
        for (int k = 0; k < KCHUNK; ++k) {
            float4 b = *(const float4*)&Ws[k * OUTC + cg * 4];
            float a[8];
#pragma unroll
            for (int i = 0; i < 8; ++i) a[i] = Xs[(mg * 8 + i) * LDX + k];
#pragma unroll
            for (int i = 0; i < 8; ++i) {
                acc[i][0] += a[i] * b.x;
                acc[i][1] += a[i] * b.y;
                acc[i][2] += a[i] * b.z;
                acc[i][3] += a[i] * b.w;
            }
        }
    }

    const float4 as4 = *(const float4*)&a_src[cg * 4];
    const float4 ad4 = *(const float4*)&a_dst[cg * 4];
    constexpr int GPH = C / 4;
    const int head = cg / GPH;
#pragma unroll
    for (int i = 0; i < 8; ++i) {
        int gn = base + mg * 8 + i;
        bool ok = gn < n;
        if (ok) {
            ushort4 hv;
            hv.x = f2bf(acc[i][0]); hv.y = f2bf(acc[i][1]);
            hv.z = f2bf(acc[i][2]); hv.w = f2bf(acc[i][3]);
            *(ushort4*)&h[(size_t)gn * OUTC + cg * 4] = hv;
        }
        float ps = acc[i][0] * as4.x + acc[i][1] * as4.y +
                   acc[i][2] * as4.z + acc[i][3] * as4.w;
        float pd = acc[i][0] * ad4.x + acc[i][1] * ad4.y +
                   acc[i][2] * ad4.z + acc[i][3] * ad4.w;
#pragma unroll
        for (int s = 1; s < GPH; s <<= 1) {
            ps += __shfl_xor(ps, s, 64);
            pd += __shfl_xor(pd, s, 64);
        }
        if (ok && (cg % GPH) == 0) {
            al_s[(size_t)gn * H + head] = ps;
            al_d[(size_t)gn * H + head] = pd;
        }
    }
}

// ------------------------- fused gather aggregation -------------------------
// wave = 1 dst node; lane = (edge_slot es, channel_group cg of 8 bf16).
// Processes 2*ES edges per iteration: both halves' srcs loads and h/al_s
// gathers are issued independently -> 16 (layer1) / 32 (layer2) gathers in
// flight per wave.
template<int H, int C>
__global__ __launch_bounds__(256)
void gat_agg_kernel(const int* __restrict__ offsets,
                    const int* __restrict__ srcs,
                    const float* __restrict__ al_s,
                    const float* __restrict__ al_d,
                    const unsigned short* __restrict__ hfeat, // bf16
                    const float* __restrict__ bias,
                    float* __restrict__ out, int n) {
    constexpr int OUTC = H * C;
    constexpr int CG   = OUTC / 8;           // channel groups (8 or 4)
    constexpr int ES   = 64 / CG;            // edge slots per half (8 or 16)
    const int wid  = (int)((blockIdx.x * blockDim.x + threadIdx.x) >> 6);
    const int lane = threadIdx.x & 63;
    const int cg   = lane % CG;
    const int es   = lane / CG;
    if (wid >= n) return;
    const int head = (cg * 8) / C;

    const float aldv = al_d[(size_t)wid * H + head];
    const int beg = offsets[wid];
    const int end = offsets[wid + 1];

    float acc[8];
#pragma unroll
    for (int q = 0; q < 8; ++q) acc[q] = 0.f;
    float dsum = 0.f;

    for (int j0 = beg; j0 < end; j0 += 2 * ES) {
        int jA = j0 + es;
        int jB = j0 + ES + es;
        bool vA = jA < end;
        bool vB = jB < end;
        int sA = __builtin_nontemporal_load(&srcs[vA ? jA : beg]);
        int sB = __builtin_nontemporal_load(&srcs[vB ? jB : beg]);
        // issue all gathers before consuming
        const uint4 hvA = *(const uint4*)&hfeat[(size_t)sA * OUTC + cg * 8];
        const uint4 hvB = *(const uint4*)&hfeat[(size_t)sB * OUTC + cg * 8];
        float lsA = al_s[(size_t)sA * H + head];
        float lsB = al_s[(size_t)sB * H + head];
        float exA = vA ? __expf(lrelu02(lsA + aldv)) : 0.f;
        float exB = vB ? __expf(lrelu02(lsB + aldv)) : 0.f;
        unsigned duA[4] = {hvA.x, hvA.y, hvA.z, hvA.w};
        unsigned duB[4] = {hvB.x, hvB.y, hvB.z, hvB.w};
#pragma unroll
        for (int q = 0; q < 4; ++q) {
            acc[2 * q]     += __uint_as_float(duA[q] << 16)         * exA;
            acc[2 * q + 1] += __uint_as_float(duA[q] & 0xffff0000u) * exA;
            acc[2 * q]     += __uint_as_float(duB[q] << 16)         * exB;
            acc[2 * q + 1] += __uint_as_float(duB[q] & 0xffff0000u) * exB;
        }
        dsum += exA + exB;
    }

#pragma unroll
    for (int sh = CG; sh < 64; sh <<= 1) {
        dsum += __shfl_xor(dsum, sh, 64);
#pragma unroll
        for (int q = 0; q < 8; ++q) acc[q] += __shfl_xor(acc[q], sh, 64);
    }

    if (es == 0) {
        float inv = 1.f / dsum;
        float4 o0, o1;
        o0.x = acc[0] * inv + bias[cg * 8 + 0];
        o0.y = acc[1] * inv + bias[cg * 8 + 1];
        o0.z = acc[2] * inv + bias[cg * 8 + 2];
        o0.w = acc[3] * inv + bias[cg * 8 + 3];
        o1.x = acc[4] * inv + bias[cg * 8 + 4];
        o1.y = acc[5] * inv + bias[cg * 8 + 5];
        o1.z = acc[6] * inv + bias[cg * 8 + 6];
        o1.w = acc[7] * inv + bias[cg * 8 + 7];
        *(float4*)&out[(size_t)wid * OUTC + cg * 8]     = o0;
        *(float4*)&out[(size_t)wid * OUTC + cg * 8 + 4] = o1;
    }
}

// ---------------------------------------------------------------------------

extern "C" void kernel_launch(void* const* d_in, const int* in_sizes, int n_in,
                              void* d_out, int out_size, void* d_ws, size_t ws_size,
                              hipStream_t stream) {
    const float* x   = (const float*)d_in[0];
    const int*   ei  = (const int*)  d_in[1];
    const float* W1  = (const float*)d_in[2];
    const float* as1 = (const float*)d_in[3];
    const float* ad1 = (const float*)d_in[4];
    const float* b1  = (const float*)d_in[5];
    const float* W2  = (const float*)d_in[6];
    const float* as2 = (const float*)d_in[7];
    const float* ad2 = (const float*)d_in[8];
    const float* b2  = (const float*)d_in[9];
    float* out = (float*)d_out;

    const int n       = in_sizes[0] / 128;   // 100000
    const int e_real  = in_sizes[1] / 2;     // 1600000
    const int e_total = e_real + n;
    // bucket(d) = umulhi(d, M256): 256 monotone dst ranges
    const unsigned M256 = (unsigned)((256ull << 32) / (unsigned)n);

    // ------------- workspace layout -------------
    unsigned short* h1u = (unsigned short*)d_ws;       // n*64 bf16 (l2: n*32)
    float* fws  = (float*)d_ws;
    float* als1 = fws  + (size_t)n * 32;               // n*8  (l2: n)
    float* ald1 = als1 + (size_t)n * 8;                // n*8  (l2: n)
    float* agg1 = ald1 + (size_t)n * 8;                // n*64 fp32 (layer1 out)
    int2*  pairs = (int2*)agg1;                        // ALIAS: e_total int2
    int* offsets  = (int*)(agg1 + (size_t)n * 64);     // n+1
    int* srcs     = offsets + (n + 1);                 // e_total
    int* bcnt_pad = srcs + e_total;                    // 256*16
    int* bcur_pad = bcnt_pad + 256 * 16;               // 256*16
    int* boff     = bcur_pad + 256 * 16;               // 257

    // ------------- CSR build (bucket sort; shared by both layers) -----------
    hipMemsetAsync(bcnt_pad, 0, 256 * 16 * sizeof(int), stream);
    bucket_hist_kernel<<<512, 256, 0, stream>>>(ei, e_real, e_total, M256,
                                                bcnt_pad);
    bucket_scan_kernel<<<1, 256, 0, stream>>>(bcnt_pad, boff, bcur_pad);
    bucket_scatter_kernel<<<(e_total + 4095) / 4096, 256, 0, stream>>>(
        ei, e_real, e_total, M256, bcur_pad, pairs);
    csr_finalize_kernel<<<256, 256, 0, stream>>>(pairs, boff, M256, n,
                                                 offsets, srcs);

    // ------------- layer 1: K=128, H=8, C=8 -------------
    gemm_al_kernel<128, 64, 8, 8, 128, 64><<<(n + 127) / 128, 256, 0, stream>>>(
        x, W1, as1, ad1, h1u, als1, ald1, n);
    gat_agg_kernel<8, 8><<<(n + 3) / 4, 256, 0, stream>>>(
        offsets, srcs, als1, ald1, h1u, b1, agg1, n);

    // ------------- layer 2: K=64, H=1, C=32 -------------
    gemm_al_kernel<64, 32, 1, 32, 256, 32><<<(n + 255) / 256, 256, 0, stream>>>(
        agg1, W2, as2, ad2, h1u, als1, ald1, n);
    gat_agg_kernel<1, 32><<<(n + 3) / 4, 256, 0, stream>>>(
        offsets, srcs, als1, ald1, h1u, b2, out, n);
}

// Round 9
// 279.042 us; speedup vs baseline: 1.4858x; 1.0790x over previous
//
#include <hip/hip_runtime.h>
#include <hip/hip_bf16.h>

// ---------------------------------------------------------------------------
// GAT (2 layers) — round 9:
//   * gat_agg: degree-specialized wave-uniform paths (deg = Poisson(16)+1):
//     <=ES half-batch; <=2ES one round; <=4ES ALL loads co-issued (one
//     latency chain); masked loop only for deg>4ES (~13 nodes). Mask ops
//     removed from hot paths.
//   * CSR: histogram pass deleted — fixed 8192-entry slab per bucket
//     (19 sigma margin), scan reads final cursors. One fewer edge sweep.
//   * rest = R8: tiled fp32 GEMM, bf16 h, bucket-sorted CSR.
// ---------------------------------------------------------------------------

#define SLAB 8192

__device__ __forceinline__ float lrelu02(float x) { return x > 0.f ? x : 0.2f * x; }

__device__ __forceinline__ unsigned short f2bf(float v) {
    __hip_bfloat16 b = __float2bfloat16(v);
    return __builtin_bit_cast(unsigned short, b);
}

__device__ __forceinline__ void accum8(uint4 hv, float ex, float* acc) {
#pragma unroll
    for (int q = 0; q < 4; ++q) {
        unsigned u = (&hv.x)[q];
        acc[2 * q]     += __uint_as_float(u << 16)         * ex;
        acc[2 * q + 1] += __uint_as_float(u & 0xffff0000u) * ex;
    }
}

// ----------------------------- CSR build (slab bucket sort) -----------------
// bucket(d) = umulhi(d, M) with M = floor(2^32*256/n): 256 monotone dst ranges.
// pairs[b*SLAB .. b*SLAB+cnt_b) holds (src,dst) of bucket b.

__global__ __launch_bounds__(256)
void bucket_scatter_kernel(const int* __restrict__ ei, int e_real, int e_total,
                           unsigned M, int* __restrict__ bcur_pad,
                           int2* __restrict__ pairs) {
    __shared__ int cnt[256], loff[256], lcur[256], gbase[256];
    __shared__ int2 stag[4096];
    __shared__ unsigned short bb[4096];
    const int t = threadIdx.x;
    const int base = blockIdx.x * 4096;
    cnt[t] = 0;
    __syncthreads();

    int rs[16], rd[16], rb[16];
#pragma unroll
    for (int k = 0; k < 16; ++k) {
        int i = base + k * 256 + t;
        bool val = i < e_total;
        int s = 0, d = 0;
        if (val) {
            if (i < e_real) { s = ei[i]; d = ei[e_real + i]; }
            else            { s = d = i - e_real; }
        }
        int b = val ? (int)__umulhi((unsigned)d, M) : -1;
        rs[k] = s; rd[k] = d; rb[k] = b;
        if (val) atomicAdd(&cnt[b], 1);
    }
    __syncthreads();

    loff[t] = cnt[t];
    __syncthreads();
    for (int off = 1; off < 256; off <<= 1) {
        int v = (t >= off) ? loff[t - off] : 0;
        __syncthreads();
        loff[t] += v;
        __syncthreads();
    }
    int excl = loff[t] - cnt[t];
    __syncthreads();
    loff[t] = excl;
    lcur[t] = excl;
    gbase[t] = t * SLAB + atomicAdd(&bcur_pad[t * 16], cnt[t]);
    __syncthreads();

#pragma unroll
    for (int k = 0; k < 16; ++k) {
        if (rb[k] >= 0) {
            int lp = atomicAdd(&lcur[rb[k]], 1);
            stag[lp] = make_int2(rs[k], rd[k]);
            bb[lp]   = (unsigned short)rb[k];
        }
    }
    __syncthreads();

    int cn = e_total - base; if (cn > 4096) cn = 4096;
    for (int idx = t; idx < cn; idx += 256) {
        int b = bb[idx];
        int g = gbase[b] + (idx - loff[b]);
        pairs[g] = stag[idx];                           // coalesced runs
    }
}

// exclusive scan of final bucket counts (in bcur_pad) -> global edge offsets
__global__ void bucket_scan_kernel(const int* __restrict__ bcur_pad,
                                   int* __restrict__ boff) {
    __shared__ int s[256];
    const int t = threadIdx.x;
    int c = bcur_pad[t * 16];
    s[t] = c;
    __syncthreads();
    for (int off = 1; off < 256; off <<= 1) {
        int v = (t >= off) ? s[t - off] : 0;
        __syncthreads();
        s[t] += v;
        __syncthreads();
    }
    boff[t] = s[t] - c;
    if (t == 255) boff[256] = s[255];
}

// one block per bucket: LDS deg+scan -> offsets; LDS-cursor scatter -> srcs.
__global__ __launch_bounds__(256)
void csr_finalize_kernel(const int2* __restrict__ pairs,
                         const int* __restrict__ boff,
                         const int* __restrict__ bcur_pad,
                         unsigned M, int n,
                         int* __restrict__ offsets,
                         int* __restrict__ srcs) {
    const int b = blockIdx.x;
    const int t = threadIdx.x;
    const unsigned long long Mll = M;
    int lo = (int)((((unsigned long long)b << 32) + Mll - 1) / Mll);
    int hi = (int)((((unsigned long long)(b + 1) << 32) + Mll - 1) / Mll);
    if (lo > n) lo = n;
    if (hi > n) hi = n;
    const int R    = hi - lo;                 // <= ~392 < 512
    const int ebeg = boff[b];
    const int cntb = bcur_pad[b * 16];
    const int2* sp = pairs + (size_t)b * SLAB;

    __shared__ int deg[512], sc[512], cur[512];
    deg[t] = 0; deg[t + 256] = 0;
    __syncthreads();
    for (int j = t; j < cntb; j += 256)
        atomicAdd(&deg[sp[j].y - lo], 1);
    __syncthreads();

    sc[t] = deg[t]; sc[t + 256] = deg[t + 256];
    __syncthreads();
    for (int off = 1; off < 512; off <<= 1) {
        int v0 = (t >= off) ? sc[t - off] : 0;
        int v1 = (t + 256 >= off) ? sc[t + 256 - off] : 0;
        __syncthreads();
        sc[t] += v0; sc[t + 256] += v1;
        __syncthreads();
    }
    int e0 = sc[t] - deg[t];
    int e1 = sc[t + 256] - deg[t + 256];
    cur[t] = e0; cur[t + 256] = e1;
    if (t < R)       offsets[lo + t]       = ebeg + e0;
    if (t + 256 < R) offsets[lo + t + 256] = ebeg + e1;
    if (b == 255 && t == 0) offsets[n] = ebeg + cntb;
    __syncthreads();

    for (int j = t; j < cntb; j += 256) {
        int2 p = sp[j];
        int pos = atomicAdd(&cur[p.y - lo], 1);         // LDS atomic
        srcs[ebeg + pos] = p.x;
    }
}

// ------------------------- tiled GEMM + attention logits --------------------
template<int K, int OUTC, int H, int C, int NPT, int KCHUNK>
__global__ __launch_bounds__(256)
void gemm_al_kernel(const float* __restrict__ x,
                    const float* __restrict__ W,
                    const float* __restrict__ a_src,
                    const float* __restrict__ a_dst,
                    unsigned short* __restrict__ h,      // [n][OUTC] bf16
                    float* __restrict__ al_s,
                    float* __restrict__ al_d,
                    int n) {
    constexpr int COLG = OUTC / 4;
    constexpr int NG   = 256 / COLG;
    static_assert(NG * 8 == NPT, "tile mismatch");
    constexpr int LDX  = KCHUNK + 1;
    __shared__ float Xs[NPT * LDX];
    __shared__ float Ws[KCHUNK * OUTC];

    const int t    = threadIdx.x;
    const int mg   = t / COLG;
    const int cg   = t % COLG;
    const int base = blockIdx.x * NPT;

    float acc[8][4];
#pragma unroll
    for (int i = 0; i < 8; ++i)
#pragma unroll
        for (int j = 0; j < 4; ++j) acc[i][j] = 0.f;

    for (int kc = 0; kc < K; kc += KCHUNK) {
        __syncthreads();
        constexpr int F4R = KCHUNK / 4;
        constexpr int TOTF4 = NPT * F4R;
#pragma unroll
        for (int r = 0; r < TOTF4 / 256; ++r) {
            int f4   = r * 256 + t;
            int node = f4 / F4R;
            int kq   = f4 % F4R;
            int gn   = base + node; if (gn > n - 1) gn = n - 1;
            const float4 v = *(const float4*)&x[(size_t)gn * K + kc + kq * 4];
            float* d = &Xs[node * LDX + kq * 4];
            d[0] = v.x; d[1] = v.y; d[2] = v.z; d[3] = v.w;
        }
        constexpr int WF4 = KCHUNK * OUTC / 4;
        for (int idx = t; idx < WF4; idx += 256)
            *(float4*)&Ws[idx * 4] = *(const float4*)&W[(size_t)kc * OUTC + idx * 4];
        __syncthreads();

#pragma unroll 4
        for (int k = 0; k < KCHUNK; ++k) {
            float4 b = *(const float4*)&Ws[k * OUTC + cg * 4];
            float a[8];
#pragma unroll
            for (int i = 0; i < 8; ++i) a[i] = Xs[(mg * 8 + i) * LDX + k];
#pragma unroll
            for (int i = 0; i < 8; ++i) {
                acc[i][0] += a[i] * b.x;
                acc[i][1] += a[i] * b.y;
                acc[i][2] += a[i] * b.z;
                acc[i][3] += a[i] * b.w;
            }
        }
    }

    const float4 as4 = *(const float4*)&a_src[cg * 4];
    const float4 ad4 = *(const float4*)&a_dst[cg * 4];
    constexpr int GPH = C / 4;
    const int head = cg / GPH;
#pragma unroll
    for (int i = 0; i < 8; ++i) {
        int gn = base + mg * 8 + i;
        bool ok = gn < n;
        if (ok) {
            ushort4 hv;
            hv.x = f2bf(acc[i][0]); hv.y = f2bf(acc[i][1]);
            hv.z = f2bf(acc[i][2]); hv.w = f2bf(acc[i][3]);
            *(ushort4*)&h[(size_t)gn * OUTC + cg * 4] = hv;
        }
        float ps = acc[i][0] * as4.x + acc[i][1] * as4.y +
                   acc[i][2] * as4.z + acc[i][3] * as4.w;
        float pd = acc[i][0] * ad4.x + acc[i][1] * ad4.y +
                   acc[i][2] * ad4.z + acc[i][3] * ad4.w;
#pragma unroll
        for (int s = 1; s < GPH; s <<= 1) {
            ps += __shfl_xor(ps, s, 64);
            pd += __shfl_xor(pd, s, 64);
        }
        if (ok && (cg % GPH) == 0) {
            al_s[(size_t)gn * H + head] = ps;
            al_d[(size_t)gn * H + head] = pd;
        }
    }
}

// ------------------------- fused gather aggregation -------------------------
// wave = 1 dst node; lane = (edge_slot es, channel_group cg of 8 bf16).
// Degree-specialized wave-uniform paths; deg = Poisson(16)+1.
template<int H, int C>
__global__ __launch_bounds__(256)
void gat_agg_kernel(const int* __restrict__ offsets,
                    const int* __restrict__ srcs,
                    const float* __restrict__ al_s,
                    const float* __restrict__ al_d,
                    const unsigned short* __restrict__ hfeat, // bf16
                    const float* __restrict__ bias,
                    float* __restrict__ out, int n) {
    constexpr int OUTC = H * C;
    constexpr int CG   = OUTC / 8;           // channel groups (8 or 4)
    constexpr int ES   = 64 / CG;            // edge slots (8 or 16)
    const int wid  = (int)((blockIdx.x * blockDim.x + threadIdx.x) >> 6);
    const int lane = threadIdx.x & 63;
    const int cg   = lane % CG;
    const int es   = lane / CG;
    if (wid >= n) return;
    const int head = (cg * 8) / C;

    const float aldv = al_d[(size_t)wid * H + head];
    const int beg = offsets[wid];
    const int end = offsets[wid + 1];
    const int deg = end - beg;

    float acc[8] = {0.f, 0.f, 0.f, 0.f, 0.f, 0.f, 0.f, 0.f};
    float dsum = 0.f;

    if (deg <= ES) {
        // one masked half-batch
        int j = beg + es;
        bool v = j < end;
        int s = __builtin_nontemporal_load(&srcs[v ? j : beg]);
        const uint4 hv = *(const uint4*)&hfeat[(size_t)s * OUTC + cg * 8];
        float ls = al_s[(size_t)s * H + head];
        float ex = v ? __expf(lrelu02(ls + aldv)) : 0.f;
        accum8(hv, ex, acc);
        dsum += ex;
    } else if (deg <= 2 * ES) {
        // A mask-free, B masked; all loads co-issued
        int sA = __builtin_nontemporal_load(&srcs[beg + es]);
        int jB = beg + ES + es;
        bool vB = jB < end;
        int sB = __builtin_nontemporal_load(&srcs[vB ? jB : beg]);
        const uint4 hvA = *(const uint4*)&hfeat[(size_t)sA * OUTC + cg * 8];
        const uint4 hvB = *(const uint4*)&hfeat[(size_t)sB * OUTC + cg * 8];
        float lsA = al_s[(size_t)sA * H + head];
        float lsB = al_s[(size_t)sB * H + head];
        float exA = __expf(lrelu02(lsA + aldv));
        float exB = vB ? __expf(lrelu02(lsB + aldv)) : 0.f;
        accum8(hvA, exA, acc);
        accum8(hvB, exB, acc);
        dsum += exA + exB;
    } else if (deg <= 4 * ES) {
        // A,B mask-free, C,D masked; all 4 batches' loads in flight at once
        int sA = __builtin_nontemporal_load(&srcs[beg + es]);
        int sB = __builtin_nontemporal_load(&srcs[beg + ES + es]);
        int jC = beg + 2 * ES + es;
        int jD = beg + 3 * ES + es;
        bool vC = jC < end;
        bool vD = jD < end;
        int sC = __builtin_nontemporal_load(&srcs[vC ? jC : beg]);
        int sD = __builtin_nontemporal_load(&srcs[vD ? jD : beg]);
        const uint4 hvA = *(const uint4*)&hfeat[(size_t)sA * OUTC + cg * 8];
        const uint4 hvB = *(const uint4*)&hfeat[(size_t)sB * OUTC + cg * 8];
        const uint4 hvC = *(const uint4*)&hfeat[(size_t)sC * OUTC + cg * 8];
        const uint4 hvD = *(const uint4*)&hfeat[(size_t)sD * OUTC + cg * 8];
        float lsA = al_s[(size_t)sA * H + head];
        float lsB = al_s[(size_t)sB * H + head];
        float lsC = al_s[(size_t)sC * H + head];
        float lsD = al_s[(size_t)sD * H + head];
        float exA = __expf(lrelu02(lsA + aldv));
        float exB = __expf(lrelu02(lsB + aldv));
        float exC = vC ? __expf(lrelu02(lsC + aldv)) : 0.f;
        float exD = vD ? __expf(lrelu02(lsD + aldv)) : 0.f;
        accum8(hvA, exA, acc);
        accum8(hvB, exB, acc);
        accum8(hvC, exC, acc);
        accum8(hvD, exD, acc);
        dsum += (exA + exB) + (exC + exD);
    } else {
        // general masked loop (rare: deg > 4*ES)
        for (int j0 = beg; j0 < end; j0 += 2 * ES) {
            int jA = j0 + es;
            int jB = j0 + ES + es;
            bool vA = jA < end;
            bool vB = jB < end;
            int sA = __builtin_nontemporal_load(&srcs[vA ? jA : beg]);
            int sB = __builtin_nontemporal_load(&srcs[vB ? jB : beg]);
            const uint4 hvA = *(const uint4*)&hfeat[(size_t)sA * OUTC + cg * 8];
            const uint4 hvB = *(const uint4*)&hfeat[(size_t)sB * OUTC + cg * 8];
            float lsA = al_s[(size_t)sA * H + head];
            float lsB = al_s[(size_t)sB * H + head];
            float exA = vA ? __expf(lrelu02(lsA + aldv)) : 0.f;
            float exB = vB ? __expf(lrelu02(lsB + aldv)) : 0.f;
            accum8(hvA, exA, acc);
            accum8(hvB, exB, acc);
            dsum += exA + exB;
        }
    }

#pragma unroll
    for (int sh = CG; sh < 64; sh <<= 1) {
        dsum += __shfl_xor(dsum, sh, 64);
#pragma unroll
        for (int q = 0; q < 8; ++q) acc[q] += __shfl_xor(acc[q], sh, 64);
    }

    if (es == 0) {
        float inv = 1.f / dsum;
        float4 o0, o1;
        o0.x = acc[0] * inv + bias[cg * 8 + 0];
        o0.y = acc[1] * inv + bias[cg * 8 + 1];
        o0.z = acc[2] * inv + bias[cg * 8 + 2];
        o0.w = acc[3] * inv + bias[cg * 8 + 3];
        o1.x = acc[4] * inv + bias[cg * 8 + 4];
        o1.y = acc[5] * inv + bias[cg * 8 + 5];
        o1.z = acc[6] * inv + bias[cg * 8 + 6];
        o1.w = acc[7] * inv + bias[cg * 8 + 7];
        *(float4*)&out[(size_t)wid * OUTC + cg * 8]     = o0;
        *(float4*)&out[(size_t)wid * OUTC + cg * 8 + 4] = o1;
    }
}

// ---------------------------------------------------------------------------

extern "C" void kernel_launch(void* const* d_in, const int* in_sizes, int n_in,
                              void* d_out, int out_size, void* d_ws, size_t ws_size,
                              hipStream_t stream) {
    const float* x   = (const float*)d_in[0];
    const int*   ei  = (const int*)  d_in[1];
    const float* W1  = (const float*)d_in[2];
    const float* as1 = (const float*)d_in[3];
    const float* ad1 = (const float*)d_in[4];
    const float* b1  = (const float*)d_in[5];
    const float* W2  = (const float*)d_in[6];
    const float* as2 = (const float*)d_in[7];
    const float* ad2 = (const float*)d_in[8];
    const float* b2  = (const float*)d_in[9];
    float* out = (float*)d_out;

    const int n       = in_sizes[0] / 128;   // 100000
    const int e_real  = in_sizes[1] / 2;     // 1600000
    const int e_total = e_real + n;
    const unsigned M256 = (unsigned)((256ull << 32) / (unsigned)n);

    // ------------- workspace layout -------------
    unsigned short* h1u = (unsigned short*)d_ws;       // n*64 bf16 (l2: n*32)
    float* fws  = (float*)d_ws;
    float* als1 = fws  + (size_t)n * 32;               // n*8  (l2: n)
    float* ald1 = als1 + (size_t)n * 8;                // n*8  (l2: n)
    float* agg1 = ald1 + (size_t)n * 8;                // n*64 fp32 (layer1 out)
    int2*  pairs = (int2*)agg1;                        // ALIAS: 256*SLAB int2
    int* offsets  = (int*)(agg1 + (size_t)n * 64);     // n+1
    int* srcs     = offsets + (n + 1);                 // e_total
    int* bcur_pad = srcs + e_total;                    // 256*16
    int* boff     = bcur_pad + 256 * 16;               // 257

    // ------------- CSR build (slab bucket sort; shared by both layers) ------
    hipMemsetAsync(bcur_pad, 0, 256 * 16 * sizeof(int), stream);
    bucket_scatter_kernel<<<(e_total + 4095) / 4096, 256, 0, stream>>>(
        ei, e_real, e_total, M256, bcur_pad, pairs);
    bucket_scan_kernel<<<1, 256, 0, stream>>>(bcur_pad, boff);
    csr_finalize_kernel<<<256, 256, 0, stream>>>(pairs, boff, bcur_pad, M256, n,
                                                 offsets, srcs);

    // ------------- layer 1: K=128, H=8, C=8 -------------
    gemm_al_kernel<128, 64, 8, 8, 128, 64><<<(n + 127) / 128, 256, 0, stream>>>(
        x, W1, as1, ad1, h1u, als1, ald1, n);
    gat_agg_kernel<8, 8><<<(n + 3) / 4, 256, 0, stream>>>(
        offsets, srcs, als1, ald1, h1u, b1, agg1, n);

    // ------------- layer 2: K=64, H=1, C=32 -------------
    gemm_al_kernel<64, 32, 1, 32, 256, 32><<<(n + 255) / 256, 256, 0, stream>>>(
        agg1, W2, as2, ad2, h1u, als1, ald1, n);
    gat_agg_kernel<1, 32><<<(n + 3) / 4, 256, 0, stream>>>(
        offsets, srcs, als1, ald1, h1u, b2, out, n);
}

// Round 10
// 278.124 us; speedup vs baseline: 1.4907x; 1.0033x over previous
//
#include <hip/hip_runtime.h>
#include <hip/hip_bf16.h>

// ---------------------------------------------------------------------------
// GAT (2 layers) — round 10:
//   * gat_agg: packed-fp32 math (float2 -> v_pk_fma_f32/v_pk_add_f32):
//     unpack bf16 pair to one float2 + single pk_fma; butterfly and epilogue
//     in float2; vector bias loads. ~30% fewer VALU instructions.
//   * CSR: bucket_scan fused into csr_finalize (per-block 256-count scan);
//     one fewer dispatch.
//   * rest = R9: slab bucket CSR, degree-specialized agg, tiled GEMM, bf16 h.
// ---------------------------------------------------------------------------

#define SLAB 8192

typedef float v2f __attribute__((ext_vector_type(2)));

__device__ __forceinline__ float lrelu02(float x) { return x > 0.f ? x : 0.2f * x; }

__device__ __forceinline__ unsigned short f2bf(float v) {
    __hip_bfloat16 b = __float2bfloat16(v);
    return __builtin_bit_cast(unsigned short, b);
}

// acc[q] += float2(lo(u_q), hi(u_q)) * ex   -- pk_fma form
__device__ __forceinline__ void accum8(uint4 hv, float ex, v2f* acc) {
    v2f ex2 = {ex, ex};
#pragma unroll
    for (int q = 0; q < 4; ++q) {
        unsigned u = (&hv.x)[q];
        v2f h2 = {__uint_as_float(u << 16), __uint_as_float(u & 0xffff0000u)};
        acc[q] = __builtin_elementwise_fma(h2, ex2, acc[q]);
    }
}

__device__ __forceinline__ v2f shfl_xor_v2(v2f v, int mask) {
    v2f r;
    r.x = __shfl_xor(v.x, mask, 64);
    r.y = __shfl_xor(v.y, mask, 64);
    return r;
}

// ----------------------------- CSR build (slab bucket sort) -----------------

__global__ __launch_bounds__(256)
void bucket_scatter_kernel(const int* __restrict__ ei, int e_real, int e_total,
                           unsigned M, int* __restrict__ bcur_pad,
                           int2* __restrict__ pairs) {
    __shared__ int cnt[256], loff[256], lcur[256], gbase[256];
    __shared__ int2 stag[4096];
    __shared__ unsigned short bb[4096];
    const int t = threadIdx.x;
    const int base = blockIdx.x * 4096;
    cnt[t] = 0;
    __syncthreads();

    int rs[16], rd[16], rb[16];
#pragma unroll
    for (int k = 0; k < 16; ++k) {
        int i = base + k * 256 + t;
        bool val = i < e_total;
        int s = 0, d = 0;
        if (val) {
            if (i < e_real) { s = ei[i]; d = ei[e_real + i]; }
            else            { s = d = i - e_real; }
        }
        int b = val ? (int)__umulhi((unsigned)d, M) : -1;
        rs[k] = s; rd[k] = d; rb[k] = b;
        if (val) atomicAdd(&cnt[b], 1);
    }
    __syncthreads();

    loff[t] = cnt[t];
    __syncthreads();
    for (int off = 1; off < 256; off <<= 1) {
        int v = (t >= off) ? loff[t - off] : 0;
        __syncthreads();
        loff[t] += v;
        __syncthreads();
    }
    int excl = loff[t] - cnt[t];
    __syncthreads();
    loff[t] = excl;
    lcur[t] = excl;
    gbase[t] = t * SLAB + atomicAdd(&bcur_pad[t * 16], cnt[t]);
    __syncthreads();

#pragma unroll
    for (int k = 0; k < 16; ++k) {
        if (rb[k] >= 0) {
            int lp = atomicAdd(&lcur[rb[k]], 1);
            stag[lp] = make_int2(rs[k], rd[k]);
            bb[lp]   = (unsigned short)rb[k];
        }
    }
    __syncthreads();

    int cn = e_total - base; if (cn > 4096) cn = 4096;
    for (int idx = t; idx < cn; idx += 256) {
        int b = bb[idx];
        int g = gbase[b] + (idx - loff[b]);
        pairs[g] = stag[idx];                           // coalesced runs
    }
}

// one block per bucket: scans all 256 bucket counts itself (no separate scan
// kernel), then LDS deg+scan -> offsets; LDS-cursor scatter -> srcs.
__global__ __launch_bounds__(256)
void csr_finalize_kernel(const int2* __restrict__ pairs,
                         const int* __restrict__ bcur_pad,
                         unsigned M, int n,
                         int* __restrict__ offsets,
                         int* __restrict__ srcs) {
    const int b = blockIdx.x;
    const int t = threadIdx.x;
    const unsigned long long Mll = M;
    int lo = (int)((((unsigned long long)b << 32) + Mll - 1) / Mll);
    int hi = (int)((((unsigned long long)(b + 1) << 32) + Mll - 1) / Mll);
    if (lo > n) lo = n;
    if (hi > n) hi = n;
    const int R    = hi - lo;                 // <= ~392 < 512
    const int cntb = bcur_pad[b * 16];
    const int2* sp = pairs + (size_t)b * SLAB;

    // block-local scan of all bucket counts -> ebeg
    __shared__ int bs[256];
    __shared__ int ebeg_s;
    bs[t] = bcur_pad[t * 16];
    __syncthreads();
    for (int off = 1; off < 256; off <<= 1) {
        int v = (t >= off) ? bs[t - off] : 0;
        __syncthreads();
        bs[t] += v;
        __syncthreads();
    }
    if (t == 0) ebeg_s = (b == 0) ? 0 : bs[b - 1];
    __syncthreads();
    const int ebeg = ebeg_s;
    if (b == 255 && t == 0) offsets[n] = bs[255];

    __shared__ int deg[512], sc[512], cur[512];
    deg[t] = 0; deg[t + 256] = 0;
    __syncthreads();
    for (int j = t; j < cntb; j += 256)
        atomicAdd(&deg[sp[j].y - lo], 1);
    __syncthreads();

    sc[t] = deg[t]; sc[t + 256] = deg[t + 256];
    __syncthreads();
    for (int off = 1; off < 512; off <<= 1) {
        int v0 = (t >= off) ? sc[t - off] : 0;
        int v1 = (t + 256 >= off) ? sc[t + 256 - off] : 0;
        __syncthreads();
        sc[t] += v0; sc[t + 256] += v1;
        __syncthreads();
    }
    int e0 = sc[t] - deg[t];
    int e1 = sc[t + 256] - deg[t + 256];
    cur[t] = e0; cur[t + 256] = e1;
    if (t < R)       offsets[lo + t]       = ebeg + e0;
    if (t + 256 < R) offsets[lo + t + 256] = ebeg + e1;
    __syncthreads();

    for (int j = t; j < cntb; j += 256) {
        int2 p = sp[j];
        int pos = atomicAdd(&cur[p.y - lo], 1);         // LDS atomic
        srcs[ebeg + pos] = p.x;
    }
}

// ------------------------- tiled GEMM + attention logits --------------------
template<int K, int OUTC, int H, int C, int NPT, int KCHUNK>
__global__ __launch_bounds__(256)
void gemm_al_kernel(const float* __restrict__ x,
                    const float* __restrict__ W,
                    const float* __restrict__ a_src,
                    const float* __restrict__ a_dst,
                    unsigned short* __restrict__ h,      // [n][OUTC] bf16
                    float* __restrict__ al_s,
                    float* __restrict__ al_d,
                    int n) {
    constexpr int COLG = OUTC / 4;
    constexpr int NG   = 256 / COLG;
    static_assert(NG * 8 == NPT, "tile mismatch");
    constexpr int LDX  = KCHUNK + 1;
    __shared__ float Xs[NPT * LDX];
    __shared__ float Ws[KCHUNK * OUTC];

    const int t    = threadIdx.x;
    const int mg   = t / COLG;
    const int cg   = t % COLG;
    const int base = blockIdx.x * NPT;

    float acc[8][4];
#pragma unroll
    for (int i = 0; i < 8; ++i)
#pragma unroll
        for (int j = 0; j < 4; ++j) acc[i][j] = 0.f;

    for (int kc = 0; kc < K; kc += KCHUNK) {
        __syncthreads();
        constexpr int F4R = KCHUNK / 4;
        constexpr int TOTF4 = NPT * F4R;
#pragma unroll
        for (int r = 0; r < TOTF4 / 256; ++r) {
            int f4   = r * 256 + t;
            int node = f4 / F4R;
            int kq   = f4 % F4R;
            int gn   = base + node; if (gn > n - 1) gn = n - 1;
            const float4 v = *(const float4*)&x[(size_t)gn * K + kc + kq * 4];
            float* d = &Xs[node * LDX + kq * 4];
            d[0] = v.x; d[1] = v.y; d[2] = v.z; d[3] = v.w;
        }
        constexpr int WF4 = KCHUNK * OUTC / 4;
        for (int idx = t; idx < WF4; idx += 256)
            *(float4*)&Ws[idx * 4] = *(const float4*)&W[(size_t)kc * OUTC + idx * 4];
        __syncthreads();

#pragma unroll 4
        for (int k = 0; k < KCHUNK; ++k) {
            float4 b = *(const float4*)&Ws[k * OUTC + cg * 4];
            float a[8];
#pragma unroll
            for (int i = 0; i < 8; ++i) a[i] = Xs[(mg * 8 + i) * LDX + k];
#pragma unroll
            for (int i = 0; i < 8; ++i) {
                acc[i][0] += a[i] * b.x;
                acc[i][1] += a[i] * b.y;
                acc[i][2] += a[i] * b.z;
                acc[i][3] += a[i] * b.w;
            }
        }
    }

    const float4 as4 = *(const float4*)&a_src[cg * 4];
    const float4 ad4 = *(const float4*)&a_dst[cg * 4];
    constexpr int GPH = C / 4;
    const int head = cg / GPH;
#pragma unroll
    for (int i = 0; i < 8; ++i) {
        int gn = base + mg * 8 + i;
        bool ok = gn < n;
        if (ok) {
            ushort4 hv;
            hv.x = f2bf(acc[i][0]); hv.y = f2bf(acc[i][1]);
            hv.z = f2bf(acc[i][2]); hv.w = f2bf(acc[i][3]);
            *(ushort4*)&h[(size_t)gn * OUTC + cg * 4] = hv;
        }
        float ps = acc[i][0] * as4.x + acc[i][1] * as4.y +
                   acc[i][2] * as4.z + acc[i][3] * as4.w;
        float pd = acc[i][0] * ad4.x + acc[i][1] * ad4.y +
                   acc[i][2] * ad4.z + acc[i][3] * ad4.w;
#pragma unroll
        for (int s = 1; s < GPH; s <<= 1) {
            ps += __shfl_xor(ps, s, 64);
            pd += __shfl_xor(pd, s, 64);
        }
        if (ok && (cg % GPH) == 0) {
            al_s[(size_t)gn * H + head] = ps;
            al_d[(size_t)gn * H + head] = pd;
        }
    }
}

// ------------------------- fused gather aggregation -------------------------
// wave = 1 dst node; lane = (edge_slot es, channel_group cg of 8 bf16).
// Degree-specialized wave-uniform paths; packed-fp32 accumulate.
template<int H, int C>
__global__ __launch_bounds__(256)
void gat_agg_kernel(const int* __restrict__ offsets,
                    const int* __restrict__ srcs,
                    const float* __restrict__ al_s,
                    const float* __restrict__ al_d,
                    const unsigned short* __restrict__ hfeat, // bf16
                    const float* __restrict__ bias,
                    float* __restrict__ out, int n) {
    constexpr int OUTC = H * C;
    constexpr int CG   = OUTC / 8;           // channel groups (8 or 4)
    constexpr int ES   = 64 / CG;            // edge slots (8 or 16)
    const int wid  = (int)((blockIdx.x * blockDim.x + threadIdx.x) >> 6);
    const int lane = threadIdx.x & 63;
    const int cg   = lane % CG;
    const int es   = lane / CG;
    if (wid >= n) return;
    const int head = (cg * 8) / C;

    const float aldv = al_d[(size_t)wid * H + head];
    const int beg = offsets[wid];
    const int end = offsets[wid + 1];
    const int deg = end - beg;

    v2f acc[4];
#pragma unroll
    for (int q = 0; q < 4; ++q) acc[q] = (v2f){0.f, 0.f};
    float dsum = 0.f;

    if (deg <= ES) {
        int j = beg + es;
        bool v = j < end;
        int s = __builtin_nontemporal_load(&srcs[v ? j : beg]);
        const uint4 hv = *(const uint4*)&hfeat[(size_t)s * OUTC + cg * 8];
        float ls = al_s[(size_t)s * H + head];
        float ex = v ? __expf(lrelu02(ls + aldv)) : 0.f;
        accum8(hv, ex, acc);
        dsum += ex;
    } else if (deg <= 2 * ES) {
        int sA = __builtin_nontemporal_load(&srcs[beg + es]);
        int jB = beg + ES + es;
        bool vB = jB < end;
        int sB = __builtin_nontemporal_load(&srcs[vB ? jB : beg]);
        const uint4 hvA = *(const uint4*)&hfeat[(size_t)sA * OUTC + cg * 8];
        const uint4 hvB = *(const uint4*)&hfeat[(size_t)sB * OUTC + cg * 8];
        float lsA = al_s[(size_t)sA * H + head];
        float lsB = al_s[(size_t)sB * H + head];
        float exA = __expf(lrelu02(lsA + aldv));
        float exB = vB ? __expf(lrelu02(lsB + aldv)) : 0.f;
        accum8(hvA, exA, acc);
        accum8(hvB, exB, acc);
        dsum += exA + exB;
    } else if (deg <= 4 * ES) {
        int sA = __builtin_nontemporal_load(&srcs[beg + es]);
        int sB = __builtin_nontemporal_load(&srcs[beg + ES + es]);
        int jC = beg + 2 * ES + es;
        int jD = beg + 3 * ES + es;
        bool vC = jC < end;
        bool vD = jD < end;
        int sC = __builtin_nontemporal_load(&srcs[vC ? jC : beg]);
        int sD = __builtin_nontemporal_load(&srcs[vD ? jD : beg]);
        const uint4 hvA = *(const uint4*)&hfeat[(size_t)sA * OUTC + cg * 8];
        const uint4 hvB = *(const uint4*)&hfeat[(size_t)sB * OUTC + cg * 8];
        const uint4 hvC = *(const uint4*)&hfeat[(size_t)sC * OUTC + cg * 8];
        const uint4 hvD = *(const uint4*)&hfeat[(size_t)sD * OUTC + cg * 8];
        float lsA = al_s[(size_t)sA * H + head];
        float lsB = al_s[(size_t)sB * H + head];
        float lsC = al_s[(size_t)sC * H + head];
        float lsD = al_s[(size_t)sD * H + head];
        float exA = __expf(lrelu02(lsA + aldv));
        float exB = __expf(lrelu02(lsB + aldv));
        float exC = vC ? __expf(lrelu02(lsC + aldv)) : 0.f;
        float exD = vD ? __expf(lrelu02(lsD + aldv)) : 0.f;
        accum8(hvA, exA, acc);
        accum8(hvB, exB, acc);
        accum8(hvC, exC, acc);
        accum8(hvD, exD, acc);
        dsum += (exA + exB) + (exC + exD);
    } else {
        for (int j0 = beg; j0 < end; j0 += 2 * ES) {
            int jA = j0 + es;
            int jB = j0 + ES + es;
            bool vA = jA < end;
            bool vB = jB < end;
            int sA = __builtin_nontemporal_load(&srcs[vA ? jA : beg]);
            int sB = __builtin_nontemporal_load(&srcs[vB ? jB : beg]);
            const uint4 hvA = *(const uint4*)&hfeat[(size_t)sA * OUTC + cg * 8];
            const uint4 hvB = *(const uint4*)&hfeat[(size_t)sB * OUTC + cg * 8];
            float lsA = al_s[(size_t)sA * H + head];
            float lsB = al_s[(size_t)sB * H + head];
            float exA = vA ? __expf(lrelu02(lsA + aldv)) : 0.f;
            float exB = vB ? __expf(lrelu02(lsB + aldv)) : 0.f;
            accum8(hvA, exA, acc);
            accum8(hvB, exB, acc);
            dsum += exA + exB;
        }
    }

    // butterfly over edge slots (packed adds)
#pragma unroll
    for (int sh = CG; sh < 64; sh <<= 1) {
        dsum += __shfl_xor(dsum, sh, 64);
#pragma unroll
        for (int q = 0; q < 4; ++q) acc[q] += shfl_xor_v2(acc[q], sh);
    }

    if (es == 0) {
        float inv = 1.f / dsum;
        const float4 b0 = *(const float4*)&bias[cg * 8];
        const float4 b1 = *(const float4*)&bias[cg * 8 + 4];
        float4 o0, o1;
        o0.x = acc[0].x * inv + b0.x;
        o0.y = acc[0].y * inv + b0.y;
        o0.z = acc[1].x * inv + b0.z;
        o0.w = acc[1].y * inv + b0.w;
        o1.x = acc[2].x * inv + b1.x;
        o1.y = acc[2].y * inv + b1.y;
        o1.z = acc[3].x * inv + b1.z;
        o1.w = acc[3].y * inv + b1.w;
        *(float4*)&out[(size_t)wid * OUTC + cg * 8]     = o0;
        *(float4*)&out[(size_t)wid * OUTC + cg * 8 + 4] = o1;
    }
}

// ---------------------------------------------------------------------------

extern "C" void kernel_launch(void* const* d_in, const int* in_sizes, int n_in,
                              void* d_out, int out_size, void* d_ws, size_t ws_size,
                              hipStream_t stream) {
    const float* x   = (const float*)d_in[0];
    const int*   ei  = (const int*)  d_in[1];
    const float* W1  = (const float*)d_in[2];
    const float* as1 = (const float*)d_in[3];
    const float* ad1 = (const float*)d_in[4];
    const float* b1  = (const float*)d_in[5];
    const float* W2  = (const float*)d_in[6];
    const float* as2 = (const float*)d_in[7];
    const float* ad2 = (const float*)d_in[8];
    const float* b2  = (const float*)d_in[9];
    float* out = (float*)d_out;

    const int n       = in_sizes[0] / 128;   // 100000
    const int e_real  = in_sizes[1] / 2;     // 1600000
    const int e_total = e_real + n;
    const unsigned M256 = (unsigned)((256ull << 32) / (unsigned)n);

    // ------------- workspace layout -------------
    unsigned short* h1u = (unsigned short*)d_ws;       // n*64 bf16 (l2: n*32)
    float* fws  = (float*)d_ws;
    float* als1 = fws  + (size_t)n * 32;               // n*8  (l2: n)
    float* ald1 = als1 + (size_t)n * 8;                // n*8  (l2: n)
    float* agg1 = ald1 + (size_t)n * 8;                // n*64 fp32 (layer1 out)
    int2*  pairs = (int2*)agg1;                        // ALIAS: 256*SLAB int2
    int* offsets  = (int*)(agg1 + (size_t)n * 64);     // n+1
    int* srcs     = offsets + (n + 1);                 // e_total
    int* bcur_pad = srcs + e_total;                    // 256*16

    // ------------- CSR build (slab bucket sort; shared by both layers) ------
    hipMemsetAsync(bcur_pad, 0, 256 * 16 * sizeof(int), stream);
    bucket_scatter_kernel<<<(e_total + 4095) / 4096, 256, 0, stream>>>(
        ei, e_real, e_total, M256, bcur_pad, pairs);
    csr_finalize_kernel<<<256, 256, 0, stream>>>(pairs, bcur_pad, M256, n,
                                                 offsets, srcs);

    // ------------- layer 1: K=128, H=8, C=8 -------------
    gemm_al_kernel<128, 64, 8, 8, 128, 64><<<(n + 127) / 128, 256, 0, stream>>>(
        x, W1, as1, ad1, h1u, als1, ald1, n);
    gat_agg_kernel<8, 8><<<(n + 3) / 4, 256, 0, stream>>>(
        offsets, srcs, als1, ald1, h1u, b1, agg1, n);

    // ------------- layer 2: K=64, H=1, C=32 -------------
    gemm_al_kernel<64, 32, 1, 32, 256, 32><<<(n + 255) / 256, 256, 0, stream>>>(
        agg1, W2, as2, ad2, h1u, als1, ald1, n);
    gat_agg_kernel<1, 32><<<(n + 3) / 4, 256, 0, stream>>>(
        offsets, srcs, als1, ald1, h1u, b2, out, n);
}

// Round 11
// 270.020 us; speedup vs baseline: 1.5355x; 1.0300x over previous
//
#include <hip/hip_runtime.h>
#include <hip/hip_bf16.h>

// ---------------------------------------------------------------------------
// GAT (2 layers) — round 11:
//   * bucket_scatter + gemm1 MERGED into one dispatch (block-role split):
//     scatter (416 mem/LDS-bound blocks) and gemm1 (782 VALU-bound blocks)
//     are independent and co-schedule on CUs -> max() instead of sum().
//   * 512 buckets (slab 4096): csr_finalize gets 2 blocks/CU (8 waves/CU)
//     for latency hiding; per-bucket node range <=196.
//   * agg kernels unchanged from R10 (structurally L3-line-service-bound).
// ---------------------------------------------------------------------------

#define SLAB  4096
#define NBUCK 512

typedef float v2f __attribute__((ext_vector_type(2)));

__device__ __forceinline__ float lrelu02(float x) { return x > 0.f ? x : 0.2f * x; }

__device__ __forceinline__ unsigned short f2bf(float v) {
    __hip_bfloat16 b = __float2bfloat16(v);
    return __builtin_bit_cast(unsigned short, b);
}

__device__ __forceinline__ void accum8(uint4 hv, float ex, v2f* acc) {
    v2f ex2 = {ex, ex};
#pragma unroll
    for (int q = 0; q < 4; ++q) {
        unsigned u = (&hv.x)[q];
        v2f h2 = {__uint_as_float(u << 16), __uint_as_float(u & 0xffff0000u)};
        acc[q] = __builtin_elementwise_fma(h2, ex2, acc[q]);
    }
}

__device__ __forceinline__ v2f shfl_xor_v2(v2f v, int mask) {
    v2f r;
    r.x = __shfl_xor(v.x, mask, 64);
    r.y = __shfl_xor(v.y, mask, 64);
    return r;
}

// ----------------------- scatter body (512-bucket slab sort) ----------------
// LDS use: cnt/loff/lcur/gbase[512] (8 KB) + stag[4096]int2 (32 KB) +
// bb[4096]u16 (8 KB) = 49152 B.
__device__ __forceinline__ void scatter_body(char* smem, int vbid,
                                             const int* __restrict__ ei,
                                             int e_real, int e_total, unsigned M,
                                             int* __restrict__ bcur_pad,
                                             int2* __restrict__ pairs) {
    int*  cnt   = (int*)smem;                    // 512
    int*  loff  = cnt + 512;                     // 512 (exclusive offsets)
    int*  lcur  = loff + 512;                    // 512
    int*  gbase = lcur + 512;                    // 512
    int2* stag  = (int2*)(gbase + 512);          // 4096
    unsigned short* bb = (unsigned short*)(stag + 4096); // 4096

    const int t = threadIdx.x;
    const int base = vbid * 4096;
    cnt[t] = 0; cnt[t + 256] = 0;
    __syncthreads();

    int rs[16], rd[16], rb[16];
#pragma unroll
    for (int k = 0; k < 16; ++k) {
        int i = base + k * 256 + t;
        bool val = i < e_total;
        int s = 0, d = 0;
        if (val) {
            if (i < e_real) { s = ei[i]; d = ei[e_real + i]; }
            else            { s = d = i - e_real; }
        }
        int b = val ? (int)__umulhi((unsigned)d, M) : -1;
        rs[k] = s; rd[k] = d; rb[k] = b;
        if (val) atomicAdd(&cnt[b], 1);
    }
    __syncthreads();

    // inclusive scan of 512 counts, 2 elements/thread
    loff[t] = cnt[t]; loff[t + 256] = cnt[t + 256];
    __syncthreads();
    for (int off = 1; off < 512; off <<= 1) {
        int v0 = (t >= off) ? loff[t - off] : 0;
        int v1 = (t + 256 >= off) ? loff[t + 256 - off] : 0;
        __syncthreads();
        loff[t] += v0; loff[t + 256] += v1;
        __syncthreads();
    }
    int e0 = loff[t] - cnt[t];
    int e1 = loff[t + 256] - cnt[t + 256];
    loff[t] = e0;           loff[t + 256] = e1;
    lcur[t] = e0;           lcur[t + 256] = e1;
    gbase[t]       = t * SLAB         + atomicAdd(&bcur_pad[t * 16], cnt[t]);
    gbase[t + 256] = (t + 256) * SLAB + atomicAdd(&bcur_pad[(t + 256) * 16],
                                                  cnt[t + 256]);
    __syncthreads();

#pragma unroll
    for (int k = 0; k < 16; ++k) {
        if (rb[k] >= 0) {
            int lp = atomicAdd(&lcur[rb[k]], 1);
            stag[lp] = make_int2(rs[k], rd[k]);
            bb[lp]   = (unsigned short)rb[k];
        }
    }
    __syncthreads();

    int cn = e_total - base; if (cn > 4096) cn = 4096;
    for (int idx = t; idx < cn; idx += 256) {
        int b = bb[idx];
        int g = gbase[b] + (idx - loff[b]);
        pairs[g] = stag[idx];                           // coalesced runs
    }
}

// ------------------------- GEMM + attention logits body ---------------------
template<int K, int OUTC, int H, int C, int NPT, int KCHUNK>
__device__ __forceinline__ void gemm_al_body(char* smem, int vbid,
                                             const float* __restrict__ x,
                                             const float* __restrict__ W,
                                             const float* __restrict__ a_src,
                                             const float* __restrict__ a_dst,
                                             unsigned short* __restrict__ h,
                                             float* __restrict__ al_s,
                                             float* __restrict__ al_d,
                                             int n) {
    constexpr int COLG = OUTC / 4;
    constexpr int NG   = 256 / COLG;
    static_assert(NG * 8 == NPT, "tile mismatch");
    constexpr int LDX  = KCHUNK + 1;
    float* Xs = (float*)smem;                 // NPT*LDX
    float* Ws = Xs + NPT * LDX;               // KCHUNK*OUTC

    const int t    = threadIdx.x;
    const int mg   = t / COLG;
    const int cg   = t % COLG;
    const int base = vbid * NPT;

    float acc[8][4];
#pragma unroll
    for (int i = 0; i < 8; ++i)
#pragma unroll
        for (int j = 0; j < 4; ++j) acc[i][j] = 0.f;

    for (int kc = 0; kc < K; kc += KCHUNK) {
        __syncthreads();
        constexpr int F4R = KCHUNK / 4;
        constexpr int TOTF4 = NPT * F4R;
#pragma unroll
        for (int r = 0; r < TOTF4 / 256; ++r) {
            int f4   = r * 256 + t;
            int node = f4 / F4R;
            int kq   = f4 % F4R;
            int gn   = base + node; if (gn > n - 1) gn = n - 1;
            const float4 v = *(const float4*)&x[(size_t)gn * K + kc + kq * 4];
            float* d = &Xs[node * LDX + kq * 4];
            d[0] = v.x; d[1] = v.y; d[2] = v.z; d[3] = v.w;
        }
        constexpr int WF4 = KCHUNK * OUTC / 4;
        for (int idx = t; idx < WF4; idx += 256)
            *(float4*)&Ws[idx * 4] = *(const float4*)&W[(size_t)kc * OUTC + idx * 4];
        __syncthreads();

#pragma unroll 4
        for (int k = 0; k < KCHUNK; ++k) {
            float4 b = *(const float4*)&Ws[k * OUTC + cg * 4];
            float a[8];
#pragma unroll
            for (int i = 0; i < 8; ++i) a[i] = Xs[(mg * 8 + i) * LDX + k];
#pragma unroll
            for (int i = 0; i < 8; ++i) {
                acc[i][0] += a[i] * b.x;
                acc[i][1] += a[i] * b.y;
                acc[i][2] += a[i] * b.z;
                acc[i][3] += a[i] * b.w;
            }
        }
    }

    const float4 as4 = *(const float4*)&a_src[cg * 4];
    const float4 ad4 = *(const float4*)&a_dst[cg * 4];
    constexpr int GPH = C / 4;
    const int head = cg / GPH;
#pragma unroll
    for (int i = 0; i < 8; ++i) {
        int gn = base + mg * 8 + i;
        bool ok = gn < n;
        if (ok) {
            ushort4 hv;
            hv.x = f2bf(acc[i][0]); hv.y = f2bf(acc[i][1]);
            hv.z = f2bf(acc[i][2]); hv.w = f2bf(acc[i][3]);
            *(ushort4*)&h[(size_t)gn * OUTC + cg * 4] = hv;
        }
        float ps = acc[i][0] * as4.x + acc[i][1] * as4.y +
                   acc[i][2] * as4.z + acc[i][3] * as4.w;
        float pd = acc[i][0] * ad4.x + acc[i][1] * ad4.y +
                   acc[i][2] * ad4.z + acc[i][3] * ad4.w;
#pragma unroll
        for (int s = 1; s < GPH; s <<= 1) {
            ps += __shfl_xor(ps, s, 64);
            pd += __shfl_xor(pd, s, 64);
        }
        if (ok && (cg % GPH) == 0) {
            al_s[(size_t)gn * H + head] = ps;
            al_d[(size_t)gn * H + head] = pd;
        }
    }
}

// ------------- merged dispatch: scatter blocks + layer-1 GEMM blocks --------
__global__ __launch_bounds__(256)
void scatter_gemm_kernel(const int* __restrict__ ei, int e_real, int e_total,
                         unsigned M, int* __restrict__ bcur_pad,
                         int2* __restrict__ pairs, int ns,
                         const float* __restrict__ x,
                         const float* __restrict__ W1,
                         const float* __restrict__ as1,
                         const float* __restrict__ ad1,
                         unsigned short* __restrict__ h,
                         float* __restrict__ al_s,
                         float* __restrict__ al_d, int n) {
    __shared__ __align__(16) char smem[49664];   // max(gemm 49664, scatter 49152)
    if ((int)blockIdx.x < ns)
        scatter_body(smem, blockIdx.x, ei, e_real, e_total, M, bcur_pad, pairs);
    else
        gemm_al_body<128, 64, 8, 8, 128, 64>(smem, blockIdx.x - ns,
                                             x, W1, as1, ad1, h, al_s, al_d, n);
}

// standalone GEMM kernel (layer 2)
template<int K, int OUTC, int H, int C, int NPT, int KCHUNK>
__global__ __launch_bounds__(256)
void gemm_al_kernel(const float* __restrict__ x, const float* __restrict__ W,
                    const float* __restrict__ a_src, const float* __restrict__ a_dst,
                    unsigned short* __restrict__ h, float* __restrict__ al_s,
                    float* __restrict__ al_d, int n) {
    __shared__ __align__(16) char smem[(NPT * (KCHUNK + 1) + KCHUNK * OUTC) * 4];
    gemm_al_body<K, OUTC, H, C, NPT, KCHUNK>(smem, blockIdx.x, x, W, a_src,
                                             a_dst, h, al_s, al_d, n);
}

// one block per bucket (512): scans bucket counts -> ebeg; LDS deg+scan ->
// offsets; LDS-cursor scatter -> srcs (single writer per srcs line).
__global__ __launch_bounds__(256)
void csr_finalize_kernel(const int2* __restrict__ pairs,
                         const int* __restrict__ bcur_pad,
                         unsigned M, int n,
                         int* __restrict__ offsets,
                         int* __restrict__ srcs) {
    const int b = blockIdx.x;
    const int t = threadIdx.x;
    const unsigned long long Mll = M;
    int lo = (int)((((unsigned long long)b << 32) + Mll - 1) / Mll);
    int hi = (int)((((unsigned long long)(b + 1) << 32) + Mll - 1) / Mll);
    if (lo > n) lo = n;
    if (hi > n) hi = n;
    const int R    = hi - lo;                 // <= ~196 < 256
    const int cntb = bcur_pad[b * 16];
    const int2* sp = pairs + (size_t)b * SLAB;

    __shared__ int bs[NBUCK];
    __shared__ int ebeg_s;
    bs[t] = bcur_pad[t * 16];
    bs[t + 256] = bcur_pad[(t + 256) * 16];
    __syncthreads();
    for (int off = 1; off < NBUCK; off <<= 1) {
        int v0 = (t >= off) ? bs[t - off] : 0;
        int v1 = (t + 256 >= off) ? bs[t + 256 - off] : 0;
        __syncthreads();
        bs[t] += v0; bs[t + 256] += v1;
        __syncthreads();
    }
    if (t == 0) ebeg_s = (b == 0) ? 0 : bs[b - 1];
    if (b == NBUCK - 1 && t == 0) offsets[n] = bs[NBUCK - 1];
    __syncthreads();
    const int ebeg = ebeg_s;

    __shared__ int deg[256], sc[256], cur[256];
    deg[t] = 0;
    __syncthreads();
    for (int j = t; j < cntb; j += 256)
        atomicAdd(&deg[sp[j].y - lo], 1);
    __syncthreads();

    sc[t] = deg[t];
    __syncthreads();
    for (int off = 1; off < 256; off <<= 1) {
        int v = (t >= off) ? sc[t - off] : 0;
        __syncthreads();
        sc[t] += v;
        __syncthreads();
    }
    int e0 = sc[t] - deg[t];
    cur[t] = e0;
    if (t < R) offsets[lo + t] = ebeg + e0;
    __syncthreads();

    for (int j = t; j < cntb; j += 256) {
        int2 p = sp[j];
        int pos = atomicAdd(&cur[p.y - lo], 1);         // LDS atomic
        srcs[ebeg + pos] = p.x;
    }
}

// ------------------------- fused gather aggregation -------------------------
template<int H, int C>
__global__ __launch_bounds__(256)
void gat_agg_kernel(const int* __restrict__ offsets,
                    const int* __restrict__ srcs,
                    const float* __restrict__ al_s,
                    const float* __restrict__ al_d,
                    const unsigned short* __restrict__ hfeat, // bf16
                    const float* __restrict__ bias,
                    float* __restrict__ out, int n) {
    constexpr int OUTC = H * C;
    constexpr int CG   = OUTC / 8;           // channel groups (8 or 4)
    constexpr int ES   = 64 / CG;            // edge slots (8 or 16)
    const int wid  = (int)((blockIdx.x * blockDim.x + threadIdx.x) >> 6);
    const int lane = threadIdx.x & 63;
    const int cg   = lane % CG;
    const int es   = lane / CG;
    if (wid >= n) return;
    const int head = (cg * 8) / C;

    const float aldv = al_d[(size_t)wid * H + head];
    const int beg = offsets[wid];
    const int end = offsets[wid + 1];
    const int deg = end - beg;

    v2f acc[4];
#pragma unroll
    for (int q = 0; q < 4; ++q) acc[q] = (v2f){0.f, 0.f};
    float dsum = 0.f;

    if (deg <= ES) {
        int j = beg + es;
        bool v = j < end;
        int s = __builtin_nontemporal_load(&srcs[v ? j : beg]);
        const uint4 hv = *(const uint4*)&hfeat[(size_t)s * OUTC + cg * 8];
        float ls = al_s[(size_t)s * H + head];
        float ex = v ? __expf(lrelu02(ls + aldv)) : 0.f;
        accum8(hv, ex, acc);
        dsum += ex;
    } else if (deg <= 2 * ES) {
        int sA = __builtin_nontemporal_load(&srcs[beg + es]);
        int jB = beg + ES + es;
        bool vB = jB < end;
        int sB = __builtin_nontemporal_load(&srcs[vB ? jB : beg]);
        const uint4 hvA = *(const uint4*)&hfeat[(size_t)sA * OUTC + cg * 8];
        const uint4 hvB = *(const uint4*)&hfeat[(size_t)sB * OUTC + cg * 8];
        float lsA = al_s[(size_t)sA * H + head];
        float lsB = al_s[(size_t)sB * H + head];
        float exA = __expf(lrelu02(lsA + aldv));
        float exB = vB ? __expf(lrelu02(lsB + aldv)) : 0.f;
        accum8(hvA, exA, acc);
        accum8(hvB, exB, acc);
        dsum += exA + exB;
    } else if (deg <= 4 * ES) {
        int sA = __builtin_nontemporal_load(&srcs[beg + es]);
        int sB = __builtin_nontemporal_load(&srcs[beg + ES + es]);
        int jC = beg + 2 * ES + es;
        int jD = beg + 3 * ES + es;
        bool vC = jC < end;
        bool vD = jD < end;
        int sC = __builtin_nontemporal_load(&srcs[vC ? jC : beg]);
        int sD = __builtin_nontemporal_load(&srcs[vD ? jD : beg]);
        const uint4 hvA = *(const uint4*)&hfeat[(size_t)sA * OUTC + cg * 8];
        const uint4 hvB = *(const uint4*)&hfeat[(size_t)sB * OUTC + cg * 8];
        const uint4 hvC = *(const uint4*)&hfeat[(size_t)sC * OUTC + cg * 8];
        const uint4 hvD = *(const uint4*)&hfeat[(size_t)sD * OUTC + cg * 8];
        float lsA = al_s[(size_t)sA * H + head];
        float lsB = al_s[(size_t)sB * H + head];
        float lsC = al_s[(size_t)sC * H + head];
        float lsD = al_s[(size_t)sD * H + head];
        float exA = __expf(lrelu02(lsA + aldv));
        float exB = __expf(lrelu02(lsB + aldv));
        float exC = vC ? __expf(lrelu02(lsC + aldv)) : 0.f;
        float exD = vD ? __expf(lrelu02(lsD + aldv)) : 0.f;
        accum8(hvA, exA, acc);
        accum8(hvB, exB, acc);
        accum8(hvC, exC, acc);
        accum8(hvD, exD, acc);
        dsum += (exA + exB) + (exC + exD);
    } else {
        for (int j0 = beg; j0 < end; j0 += 2 * ES) {
            int jA = j0 + es;
            int jB = j0 + ES + es;
            bool vA = jA < end;
            bool vB = jB < end;
            int sA = __builtin_nontemporal_load(&srcs[vA ? jA : beg]);
            int sB = __builtin_nontemporal_load(&srcs[vB ? jB : beg]);
            const uint4 hvA = *(const uint4*)&hfeat[(size_t)sA * OUTC + cg * 8];
            const uint4 hvB = *(const uint4*)&hfeat[(size_t)sB * OUTC + cg * 8];
            float lsA = al_s[(size_t)sA * H + head];
            float lsB = al_s[(size_t)sB * H + head];
            float exA = vA ? __expf(lrelu02(lsA + aldv)) : 0.f;
            float exB = vB ? __expf(lrelu02(lsB + aldv)) : 0.f;
            accum8(hvA, exA, acc);
            accum8(hvB, exB, acc);
            dsum += exA + exB;
        }
    }

#pragma unroll
    for (int sh = CG; sh < 64; sh <<= 1) {
        dsum += __shfl_xor(dsum, sh, 64);
#pragma unroll
        for (int q = 0; q < 4; ++q) acc[q] += shfl_xor_v2(acc[q], sh);
    }

    if (es == 0) {
        float inv = 1.f / dsum;
        const float4 b0 = *(const float4*)&bias[cg * 8];
        const float4 b1 = *(const float4*)&bias[cg * 8 + 4];
        float4 o0, o1;
        o0.x = acc[0].x * inv + b0.x;
        o0.y = acc[0].y * inv + b0.y;
        o0.z = acc[1].x * inv + b0.z;
        o0.w = acc[1].y * inv + b0.w;
        o1.x = acc[2].x * inv + b1.x;
        o1.y = acc[2].y * inv + b1.y;
        o1.z = acc[3].x * inv + b1.z;
        o1.w = acc[3].y * inv + b1.w;
        *(float4*)&out[(size_t)wid * OUTC + cg * 8]     = o0;
        *(float4*)&out[(size_t)wid * OUTC + cg * 8 + 4] = o1;
    }
}

// ---------------------------------------------------------------------------

extern "C" void kernel_launch(void* const* d_in, const int* in_sizes, int n_in,
                              void* d_out, int out_size, void* d_ws, size_t ws_size,
                              hipStream_t stream) {
    const float* x   = (const float*)d_in[0];
    const int*   ei  = (const int*)  d_in[1];
    const float* W1  = (const float*)d_in[2];
    const float* as1 = (const float*)d_in[3];
    const float* ad1 = (const float*)d_in[4];
    const float* b1  = (const float*)d_in[5];
    const float* W2  = (const float*)d_in[6];
    const float* as2 = (const float*)d_in[7];
    const float* ad2 = (const float*)d_in[8];
    const float* b2  = (const float*)d_in[9];
    float* out = (float*)d_out;

    const int n       = in_sizes[0] / 128;   // 100000
    const int e_real  = in_sizes[1] / 2;     // 1600000
    const int e_total = e_real + n;
    const unsigned M512 = (unsigned)(((unsigned long long)NBUCK << 32) / (unsigned)n);

    // ------------- workspace layout -------------
    unsigned short* h1u = (unsigned short*)d_ws;       // n*64 bf16 (l2: n*32)
    float* fws  = (float*)d_ws;
    float* als1 = fws  + (size_t)n * 32;               // n*8  (l2: n)
    float* ald1 = als1 + (size_t)n * 8;                // n*8  (l2: n)
    float* agg1 = ald1 + (size_t)n * 8;                // n*64 fp32 (layer1 out)
    int2*  pairs = (int2*)agg1;                        // ALIAS: NBUCK*SLAB int2
    int* offsets  = (int*)(agg1 + (size_t)n * 64);     // n+1
    int* srcs     = offsets + (n + 1);                 // e_total
    int* bcur_pad = srcs + e_total;                    // NBUCK*16

    const int ns = (e_total + 4095) / 4096;            // scatter blocks (416)
    const int g1 = (n + 127) / 128;                    // gemm1 blocks (782)

    // ------------- CSR build + layer-1 GEMM (merged) -------------
    hipMemsetAsync(bcur_pad, 0, NBUCK * 16 * sizeof(int), stream);
    scatter_gemm_kernel<<<ns + g1, 256, 0, stream>>>(
        ei, e_real, e_total, M512, bcur_pad, pairs, ns,
        x, W1, as1, ad1, h1u, als1, ald1, n);
    csr_finalize_kernel<<<NBUCK, 256, 0, stream>>>(pairs, bcur_pad, M512, n,
                                                   offsets, srcs);

    // ------------- layer 1 aggregation -------------
    gat_agg_kernel<8, 8><<<(n + 3) / 4, 256, 0, stream>>>(
        offsets, srcs, als1, ald1, h1u, b1, agg1, n);

    // ------------- layer 2: K=64, H=1, C=32 -------------
    gemm_al_kernel<64, 32, 1, 32, 256, 32><<<(n + 255) / 256, 256, 0, stream>>>(
        agg1, W2, as2, ad2, h1u, als1, ald1, n);
    gat_agg_kernel<1, 32><<<(n + 3) / 4, 256, 0, stream>>>(
        offsets, srcs, als1, ald1, h1u, b2, out, n);
}